// Round 2
// baseline (29773.355 us; speedup 1.0000x reference)
//
#include <hip/hip_runtime.h>

// ---------------- problem constants ----------------
constexpr int cB = 32, cS = 512, cH = 768, cL = 6, cNH = 12, cFF = 3072, cT = 7;
constexpr int cM = cB * cS;     // 16384 tokens
constexpr int cDH = cH / cNH;   // 64

#define DEVI __device__ __forceinline__

typedef __attribute__((ext_vector_type(8))) short bh8_t;  // 8 bf16 (4 VGPRs)
typedef __attribute__((ext_vector_type(4))) float f4_t;   // MFMA accumulator

DEVI unsigned short f2bf(float f) {
  unsigned int u = __float_as_uint(f);
  return (unsigned short)((u + 0x7fffu + ((u >> 16) & 1u)) >> 16);
}
DEVI float bf2f(unsigned short h) { return __uint_as_float(((unsigned int)h) << 16); }

typedef __attribute__((address_space(1))) void* gas_t;
typedef __attribute__((address_space(3))) void* las_t;
DEVI void async16(void* lds, const void* g) {
  __builtin_amdgcn_global_load_lds((gas_t)g, (las_t)lds, 16, 0, 0);
}

// ---------------- weight transpose fp32(K,N) -> bf16(N,K) ----------------
__global__ void wtrans(const float* __restrict__ in, unsigned short* __restrict__ out,
                       int K, int N) {
  __shared__ float tile[32][33];
  const int tx = threadIdx.x, ty = threadIdx.y;          // block (32,8)
  const int n0 = blockIdx.x * 32, k0 = blockIdx.y * 32;
#pragma unroll
  for (int i = 0; i < 4; i++)
    tile[ty + i * 8][tx] = in[(size_t)(k0 + ty + i * 8) * N + n0 + tx];
  __syncthreads();
#pragma unroll
  for (int i = 0; i < 4; i++)
    out[(size_t)(n0 + ty + i * 8) * K + k0 + tx] = f2bf(tile[tx][ty + i * 8]);
}

// ---------------- bf16 MFMA GEMM: C(M,N) = A(M,K) * Bt(N,K)^T ----------------
// 128x128 tile, BK=32, 256 threads (2x2 waves, each 64x64 via 4x4 mfma 16x16x32)
// RESID path: outf may alias resid (same-thread same-index read-then-write).
template <bool RESID, bool GELU, bool OUTB>
__global__ __launch_bounds__(256) void gemm_bf16(
    const unsigned short* __restrict__ A, const unsigned short* __restrict__ Bt,
    const float* __restrict__ bias, const float* resid,
    float* outf, unsigned short* __restrict__ outb, int N, int K) {
  __shared__ __align__(16) unsigned short As[128 * 32];
  __shared__ __align__(16) unsigned short Bs[128 * 32];
  const int tid = threadIdx.x;
  const int lane = tid & 63;
  const int wave = tid >> 6;
  const int wm = wave >> 1, wn = wave & 1;
  const int m0 = blockIdx.y * 128;
  const int n0 = blockIdx.x * 128;

  f4_t acc[4][4] = {};

  const int rA = tid >> 2;            // staging row within 64-row half
  const int cA = (tid & 3) << 3;      // staging col (bf16 elems)
  const unsigned short* gA0 = A + (size_t)(m0 + rA) * K + cA;
  const unsigned short* gA1 = A + (size_t)(m0 + 64 + rA) * K + cA;
  const unsigned short* gB0 = Bt + (size_t)(n0 + rA) * K + cA;
  const unsigned short* gB1 = Bt + (size_t)(n0 + 64 + rA) * K + cA;
  unsigned short* lA0 = As + wave * 512;
  unsigned short* lA1 = As + 2048 + wave * 512;
  unsigned short* lB0 = Bs + wave * 512;
  unsigned short* lB1 = Bs + 2048 + wave * 512;
  const unsigned short* fA = As + (wm * 64 + (lane & 15)) * 32 + ((lane >> 4) << 3);
  const unsigned short* fB = Bs + (wn * 64 + (lane & 15)) * 32 + ((lane >> 4) << 3);

  for (int k0 = 0; k0 < K; k0 += 32) {
    async16(lA0, gA0 + k0);
    async16(lA1, gA1 + k0);
    async16(lB0, gB0 + k0);
    async16(lB1, gB1 + k0);
    __syncthreads();  // drains vmcnt for global_load_lds before reads
    bh8_t af[4], bfr[4];
#pragma unroll
    for (int i = 0; i < 4; i++) af[i] = *(const bh8_t*)(fA + i * 512);
#pragma unroll
    for (int i = 0; i < 4; i++) bfr[i] = *(const bh8_t*)(fB + i * 512);
#pragma unroll
    for (int mi = 0; mi < 4; mi++)
#pragma unroll
      for (int ni = 0; ni < 4; ni++)
        acc[mi][ni] = __builtin_amdgcn_mfma_f32_16x16x32_bf16(af[mi], bfr[ni],
                                                              acc[mi][ni], 0, 0, 0);
    __syncthreads();  // reads done before next overwrite
  }

#pragma unroll
  for (int mi = 0; mi < 4; mi++) {
    const int row = m0 + wm * 64 + mi * 16 + ((lane >> 4) << 2);
#pragma unroll
    for (int ni = 0; ni < 4; ni++) {
      const int col = n0 + wn * 64 + ni * 16 + (lane & 15);
      const float bv = bias[col];
#pragma unroll
      for (int r = 0; r < 4; r++) {
        const size_t idx = (size_t)(row + r) * N + col;
        float v = acc[mi][ni][r] + bv;
        if (RESID) v += resid[idx];
        if (GELU) v = 0.5f * v * (1.0f + erff(v * 0.70710678118654752f));
        if (OUTB) outb[idx] = f2bf(v);
        else outf[idx] = v;
      }
    }
  }
}

// ---------------- embedding + LayerNorm (fused) ----------------
__global__ __launch_bounds__(256) void embed_ln(
    const int* __restrict__ ids, const float* __restrict__ wemb,
    const float* __restrict__ pemb, const float* __restrict__ g,
    const float* __restrict__ be, float* __restrict__ xo,
    unsigned short* __restrict__ xbo) {
  const int token = blockIdx.x;
  const int tid = threadIdx.x;
  const int id = ids[token];
  const int pos = token & (cS - 1);
  const float* wr = wemb + (size_t)id * cH;
  const float* pr = pemb + (size_t)pos * cH;
  float v[3];
#pragma unroll
  for (int i = 0; i < 3; i++) v[i] = wr[tid + i * 256] + pr[tid + i * 256];
  float s = v[0] + v[1] + v[2];
  float s2 = v[0] * v[0] + v[1] * v[1] + v[2] * v[2];
#pragma unroll
  for (int off = 32; off; off >>= 1) { s += __shfl_xor(s, off); s2 += __shfl_xor(s2, off); }
  __shared__ float sa[4], sb[4];
  if ((tid & 63) == 0) { sa[tid >> 6] = s; sb[tid >> 6] = s2; }
  __syncthreads();
  s = sa[0] + sa[1] + sa[2] + sa[3];
  s2 = sb[0] + sb[1] + sb[2] + sb[3];
  const float mean = s * (1.0f / cH);
  const float rstd = rsqrtf(s2 * (1.0f / cH) - mean * mean + 1e-12f);
  float* xr = xo + (size_t)token * cH;
  unsigned short* xbr = xbo + (size_t)token * cH;
#pragma unroll
  for (int i = 0; i < 3; i++) {
    const int c = tid + i * 256;
    const float nv = (v[i] - mean) * rstd * g[c] + be[c];
    xr[c] = nv;
    xbr[c] = f2bf(nv);
  }
}

// ---------------- in-place LayerNorm: x -> x (fp32) + xb (bf16) ----------------
__global__ __launch_bounds__(256) void ln_fused(
    float* __restrict__ x, const float* __restrict__ g,
    const float* __restrict__ be, unsigned short* __restrict__ xbo) {
  const int token = blockIdx.x;
  const int tid = threadIdx.x;
  float* row = x + (size_t)token * cH;
  float v[3];
#pragma unroll
  for (int i = 0; i < 3; i++) v[i] = row[tid + i * 256];
  float s = v[0] + v[1] + v[2];
  float s2 = v[0] * v[0] + v[1] * v[1] + v[2] * v[2];
#pragma unroll
  for (int off = 32; off; off >>= 1) { s += __shfl_xor(s, off); s2 += __shfl_xor(s2, off); }
  __shared__ float sa[4], sb[4];
  if ((tid & 63) == 0) { sa[tid >> 6] = s; sb[tid >> 6] = s2; }
  __syncthreads();
  s = sa[0] + sa[1] + sa[2] + sa[3];
  s2 = sb[0] + sb[1] + sb[2] + sb[3];
  const float mean = s * (1.0f / cH);
  const float rstd = rsqrtf(s2 * (1.0f / cH) - mean * mean + 1e-12f);
  unsigned short* xbr = xbo + (size_t)token * cH;
#pragma unroll
  for (int i = 0; i < 3; i++) {
    const int c = tid + i * 256;
    const float nv = (v[i] - mean) * rstd * g[c] + be[c];
    row[c] = nv;
    xbr[c] = f2bf(nv);
  }
}

// ---------------- attention: one wave per query, online softmax ----------------
__global__ __launch_bounds__(256) void attn(
    const unsigned short* __restrict__ qg, const unsigned short* __restrict__ kg,
    const unsigned short* __restrict__ vg, const int* __restrict__ amask,
    unsigned short* __restrict__ ctxb) {
  const int wg = blockIdx.x * 4 + (threadIdx.x >> 6);
  const int lane = threadIdx.x & 63;
  const int q = wg & (cS - 1);
  const int h = (wg >> 9) % cNH;
  const int b = wg / (cS * cNH);

  const int* mrow = amask + b * cS;
  int cnt = 0;
#pragma unroll
  for (int i = 0; i < 8; i++) cnt += mrow[lane + i * 64];
#pragma unroll
  for (int off = 32; off; off >>= 1) cnt += __shfl_xor(cnt, off);
  const int len = cnt;

  unsigned short* outp = ctxb + (size_t)(b * cS + q) * cH + h * cDH + lane;
  if (q >= len) { *outp = 0; return; }  // padded query: loss-irrelevant, avoid NaN

  const float qv = bf2f(qg[(size_t)(b * cS + q) * cH + h * cDH + lane]) * 0.125f;
  const unsigned short* kr = kg + (size_t)(b * cS) * cH + h * cDH + lane;
  const unsigned short* vr = vg + (size_t)(b * cS) * cH + h * cDH + lane;
  float m = -3.0e38f, l = 0.0f, o = 0.0f;
  for (int j = 0; j < len; j++) {
    float p = qv * bf2f(kr[(size_t)j * cH]);
#pragma unroll
    for (int off = 32; off; off >>= 1) p += __shfl_xor(p, off);
    const float mn = fmaxf(m, p);
    const float sc = __expf(m - mn);
    const float e = __expf(p - mn);
    const float vv = bf2f(vr[(size_t)j * cH]);
    l = l * sc + e;
    o = o * sc + e * vv;
    m = mn;
  }
  *outp = f2bf(o / l);
}

// ---------------- classifier head: emissions = x @ cls_w + cls_b ----------------
__global__ __launch_bounds__(256) void cls_head(
    const float* __restrict__ x, const float* __restrict__ w,
    const float* __restrict__ cb, float* __restrict__ em) {
  const int token = blockIdx.x * 4 + (threadIdx.x >> 6);
  const int lane = threadIdx.x & 63;
  const float* xr = x + (size_t)token * cH;
  float p[cT] = {};
  for (int k = lane; k < cH; k += 64) {
    const float xv = xr[k];
    const float* wr = w + k * cT;
#pragma unroll
    for (int t = 0; t < cT; t++) p[t] += xv * wr[t];
  }
#pragma unroll
  for (int t = 0; t < cT; t++) {
    float r = p[t];
#pragma unroll
    for (int off = 32; off; off >>= 1) r += __shfl_xor(r, off);
    if (lane == t) em[(size_t)token * cT + t] = r + cb[t];
  }
}

// ---------------- CRF NLL: one wave per sequence ----------------
__global__ __launch_bounds__(256) void crf(
    const float* __restrict__ em, const int* __restrict__ labels,
    const float* __restrict__ cstart, const float* __restrict__ cend,
    const float* __restrict__ ctrans, float* __restrict__ out) {
  const int b = blockIdx.x * 4 + (threadIdx.x >> 6);
  const int lane = threadIdx.x & 63;
  const int* lab = labels + b * cS;
  const float* eb = em + (size_t)b * cS * cT;

  // numerator (distributed over lanes)
  float numpart = 0.0f;
  int cntpart = 0;
  for (int s = lane; s < cS; s += 64) {
    const int lb = lab[s];
    const bool valid = (s == 0) || (lb != -100);
    if (valid) {
      cntpart++;
      if (s > 0) numpart += ctrans[lab[s - 1] * cT + lb] + eb[s * cT + lb];
    }
  }
#pragma unroll
  for (int off = 32; off; off >>= 1) {
    numpart += __shfl_xor(numpart, off);
    cntpart += __shfl_xor(cntpart, off);
  }
  const int len = cntpart;
  const int l0 = lab[0];
  const float num = numpart + cstart[l0] + eb[l0] + cend[lab[len - 1]];

  // denominator: forward algorithm, lane j<7 holds alpha_j
  float trj[cT];
  float alpha = -3.0e38f;
  if (lane < cT) {
#pragma unroll
    for (int i = 0; i < cT; i++) trj[i] = ctrans[i * cT + lane];
    alpha = cstart[lane] + eb[lane];
  } else {
#pragma unroll
    for (int i = 0; i < cT; i++) trj[i] = 0.0f;
  }
  for (int s = 1; s < cS; s++) {
    if (lab[s] == -100) break;  // mask is a contiguous prefix; alpha frozen after
    const float ema = (lane < cT) ? eb[s * cT + lane] : 0.0f;
    float tv[cT], mx = -3.0e38f;
#pragma unroll
    for (int i = 0; i < cT; i++) {
      tv[i] = __shfl(alpha, i) + trj[i];
      mx = fmaxf(mx, tv[i]);
    }
    float ss = 0.0f;
#pragma unroll
    for (int i = 0; i < cT; i++) ss += __expf(tv[i] - mx);
    const float nxt = mx + __logf(ss) + ema;
    if (lane < cT) alpha = nxt;
  }
  float val = (lane < cT) ? alpha + cend[lane] : -3.0e38f;
  float mx = val;
#pragma unroll
  for (int off = 32; off; off >>= 1) mx = fmaxf(mx, __shfl_xor(mx, off));
  float se = __expf(val - mx);
#pragma unroll
  for (int off = 32; off; off >>= 1) se += __shfl_xor(se, off);
  if (lane == 0) atomicAdd(out, (mx + __logf(se) - num) * (1.0f / cB));
}

// ---------------- launch ----------------
extern "C" void kernel_launch(void* const* d_in, const int* in_sizes, int n_in,
                              void* d_out, int out_size, void* d_ws, size_t ws_size,
                              hipStream_t stream) {
  const float* word_emb = (const float*)d_in[0];
  const float* pos_emb = (const float*)d_in[1];
  const float* emb_ln_s = (const float*)d_in[2];
  const float* emb_ln_b = (const float*)d_in[3];
  const float* attn_qw = (const float*)d_in[4];
  const float* attn_qb = (const float*)d_in[5];
  const float* attn_kw = (const float*)d_in[6];
  const float* attn_kb = (const float*)d_in[7];
  const float* attn_vw = (const float*)d_in[8];
  const float* attn_vb = (const float*)d_in[9];
  const float* attn_ow = (const float*)d_in[10];
  const float* attn_ob = (const float*)d_in[11];
  const float* ln1_s = (const float*)d_in[12];
  const float* ln1_b = (const float*)d_in[13];
  const float* ffn_w1 = (const float*)d_in[14];
  const float* ffn_b1 = (const float*)d_in[15];
  const float* ffn_w2 = (const float*)d_in[16];
  const float* ffn_b2 = (const float*)d_in[17];
  const float* ln2_s = (const float*)d_in[18];
  const float* ln2_b = (const float*)d_in[19];
  const float* cls_w = (const float*)d_in[20];
  const float* cls_b = (const float*)d_in[21];
  const float* crf_start = (const float*)d_in[22];
  const float* crf_end = (const float*)d_in[23];
  const float* crf_trans = (const float*)d_in[24];
  const int* input_ids = (const int*)d_in[25];
  const int* amask = (const int*)d_in[26];
  const int* labels = (const int*)d_in[27];

  // ---- workspace layout (~191 MB total; keep minimal — ws_size is opaque) ----
  char* ws = (char*)d_ws;
  size_t off = 0;
  auto alloc = [&](size_t bytes) -> void* {
    void* p = ws + off;
    off += (bytes + 255) & ~(size_t)255;
    return p;
  };
  constexpr size_t LW = 7077888;  // bf16 elems of one layer's transposed weights
  unsigned short* Wt = (unsigned short*)alloc(LW * 2);                  // 14.2 MB
  float* x = (float*)alloc((size_t)cM * cH * 4);                        // 50.3 MB
  unsigned short* xb = (unsigned short*)alloc((size_t)cM * cH * 2);     // 25.2 MB
  // union region: {qb,kbuf,vbuf,ctx} (attention phase) vs hb (FFN phase)
  unsigned short* un = (unsigned short*)alloc((size_t)cM * cFF * 2);    // 100.7 MB
  unsigned short* qb = un;
  unsigned short* kbuf = un + (size_t)cM * cH;
  unsigned short* vbuf = un + (size_t)2 * cM * cH;
  unsigned short* ctx = un + (size_t)3 * cM * cH;
  unsigned short* hb = un;
  float* emis = (float*)alloc((size_t)cM * cT * 4);                     // 0.5 MB

  hipMemsetAsync(d_out, 0, sizeof(float) * out_size, stream);

  embed_ln<<<cM, 256, 0, stream>>>(input_ids, word_emb, pos_emb, emb_ln_s, emb_ln_b, x, xb);

  const dim3 tb(32, 8);
  for (int i = 0; i < cL; i++) {
    // stage this layer's weights (transposed, bf16) into the single-layer buffer
    wtrans<<<dim3(cH / 32, cH / 32), tb, 0, stream>>>(attn_qw + (size_t)i * cH * cH, Wt + 0, cH, cH);
    wtrans<<<dim3(cH / 32, cH / 32), tb, 0, stream>>>(attn_kw + (size_t)i * cH * cH, Wt + 589824, cH, cH);
    wtrans<<<dim3(cH / 32, cH / 32), tb, 0, stream>>>(attn_vw + (size_t)i * cH * cH, Wt + 1179648, cH, cH);
    wtrans<<<dim3(cH / 32, cH / 32), tb, 0, stream>>>(attn_ow + (size_t)i * cH * cH, Wt + 1769472, cH, cH);
    wtrans<<<dim3(cFF / 32, cH / 32), tb, 0, stream>>>(ffn_w1 + (size_t)i * cH * cFF, Wt + 2359296, cH, cFF);
    wtrans<<<dim3(cH / 32, cFF / 32), tb, 0, stream>>>(ffn_w2 + (size_t)i * cFF * cH, Wt + 4718592, cFF, cH);

    gemm_bf16<false, false, true><<<dim3(cH / 128, cM / 128), 256, 0, stream>>>(
        xb, Wt + 0, attn_qb + i * cH, nullptr, nullptr, qb, cH, cH);
    gemm_bf16<false, false, true><<<dim3(cH / 128, cM / 128), 256, 0, stream>>>(
        xb, Wt + 589824, attn_kb + i * cH, nullptr, nullptr, kbuf, cH, cH);
    gemm_bf16<false, false, true><<<dim3(cH / 128, cM / 128), 256, 0, stream>>>(
        xb, Wt + 1179648, attn_vb + i * cH, nullptr, nullptr, vbuf, cH, cH);
    attn<<<cB * cNH * cS / 4, 256, 0, stream>>>(qb, kbuf, vbuf, amask, ctx);
    gemm_bf16<true, false, false><<<dim3(cH / 128, cM / 128), 256, 0, stream>>>(
        ctx, Wt + 1769472, attn_ob + i * cH, x, x, nullptr, cH, cH);  // x += ctx@Wo+b (in place)
    ln_fused<<<cM, 256, 0, stream>>>(x, ln1_s + i * cH, ln1_b + i * cH, xb);
    gemm_bf16<false, true, true><<<dim3(cFF / 128, cM / 128), 256, 0, stream>>>(
        xb, Wt + 2359296, ffn_b1 + i * cFF, nullptr, nullptr, hb, cFF, cH);
    gemm_bf16<true, false, false><<<dim3(cH / 128, cM / 128), 256, 0, stream>>>(
        hb, Wt + 4718592, ffn_b2 + i * cH, x, x, nullptr, cH, cFF);   // x += h@W2+b (in place)
    ln_fused<<<cM, 256, 0, stream>>>(x, ln2_s + i * cH, ln2_b + i * cH, xb);
  }

  cls_head<<<cM / 4, 256, 0, stream>>>(x, cls_w, cls_b, emis);
  crf<<<cB / 4, 256, 0, stream>>>(emis, labels, crf_start, crf_end, crf_trans, (float*)d_out);
}

// Round 3
// 3848.470 us; speedup vs baseline: 7.7364x; 7.7364x over previous
//
#include <hip/hip_runtime.h>

// ---------------- problem constants ----------------
constexpr int cB = 32, cS = 512, cH = 768, cL = 6, cNH = 12, cFF = 3072, cT = 7;
constexpr int cM = cB * cS;     // 16384 tokens
constexpr int cDH = cH / cNH;   // 64

#define DEVI __device__ __forceinline__

typedef __attribute__((ext_vector_type(8))) short bh8_t;  // 8 bf16 (4 VGPRs)
typedef __attribute__((ext_vector_type(4))) float f4_t;   // MFMA accumulator

DEVI unsigned short f2bf(float f) {
  unsigned int u = __float_as_uint(f);
  return (unsigned short)((u + 0x7fffu + ((u >> 16) & 1u)) >> 16);
}
DEVI float bf2f(unsigned short h) { return __uint_as_float(((unsigned int)h) << 16); }

typedef __attribute__((address_space(1))) void* gas_t;
typedef __attribute__((address_space(3))) void* las_t;
DEVI void async16(void* lds, const void* g) {
  __builtin_amdgcn_global_load_lds((gas_t)g, (las_t)lds, 16, 0, 0);
}

// ---------------- weight transpose fp32(K,N) -> bf16(N,K) ----------------
__global__ void wtrans(const float* __restrict__ in, unsigned short* __restrict__ out,
                       int K, int N) {
  __shared__ float tile[32][33];
  const int tx = threadIdx.x, ty = threadIdx.y;          // block (32,8)
  const int n0 = blockIdx.x * 32, k0 = blockIdx.y * 32;
#pragma unroll
  for (int i = 0; i < 4; i++)
    tile[ty + i * 8][tx] = in[(size_t)(k0 + ty + i * 8) * N + n0 + tx];
  __syncthreads();
#pragma unroll
  for (int i = 0; i < 4; i++)
    out[(size_t)(n0 + ty + i * 8) * K + k0 + tx] = f2bf(tile[tx][ty + i * 8]);
}

// ---------------- bf16 MFMA GEMM: C(M,N) = A(M,K) * Bt(N,K)^T ----------------
// 128x128 tile, BK=32, 256 threads (2x2 waves, each 64x64 via 4x4 mfma 16x16x32)
// RESID path: outf may alias resid (same-thread same-index read-then-write).
template <bool RESID, bool GELU, bool OUTB>
__global__ __launch_bounds__(256) void gemm_bf16(
    const unsigned short* __restrict__ A, const unsigned short* __restrict__ Bt,
    const float* __restrict__ bias, const float* resid,
    float* outf, unsigned short* __restrict__ outb, int N, int K) {
  __shared__ __align__(16) unsigned short As[128 * 32];
  __shared__ __align__(16) unsigned short Bs[128 * 32];
  const int tid = threadIdx.x;
  const int lane = tid & 63;
  const int wave = tid >> 6;
  const int wm = wave >> 1, wn = wave & 1;
  const int m0 = blockIdx.y * 128;
  const int n0 = blockIdx.x * 128;

  f4_t acc[4][4] = {};

  const int rA = tid >> 2;            // staging row within 64-row half
  const int cA = (tid & 3) << 3;      // staging col (bf16 elems)
  const unsigned short* gA0 = A + (size_t)(m0 + rA) * K + cA;
  const unsigned short* gA1 = A + (size_t)(m0 + 64 + rA) * K + cA;
  const unsigned short* gB0 = Bt + (size_t)(n0 + rA) * K + cA;
  const unsigned short* gB1 = Bt + (size_t)(n0 + 64 + rA) * K + cA;
  unsigned short* lA0 = As + wave * 512;
  unsigned short* lA1 = As + 2048 + wave * 512;
  unsigned short* lB0 = Bs + wave * 512;
  unsigned short* lB1 = Bs + 2048 + wave * 512;
  const unsigned short* fA = As + (wm * 64 + (lane & 15)) * 32 + ((lane >> 4) << 3);
  const unsigned short* fB = Bs + (wn * 64 + (lane & 15)) * 32 + ((lane >> 4) << 3);

  for (int k0 = 0; k0 < K; k0 += 32) {
    async16(lA0, gA0 + k0);
    async16(lA1, gA1 + k0);
    async16(lB0, gB0 + k0);
    async16(lB1, gB1 + k0);
    __syncthreads();  // drains vmcnt for global_load_lds before reads
    bh8_t af[4], bfr[4];
#pragma unroll
    for (int i = 0; i < 4; i++) af[i] = *(const bh8_t*)(fA + i * 512);
#pragma unroll
    for (int i = 0; i < 4; i++) bfr[i] = *(const bh8_t*)(fB + i * 512);
#pragma unroll
    for (int mi = 0; mi < 4; mi++)
#pragma unroll
      for (int ni = 0; ni < 4; ni++)
        acc[mi][ni] = __builtin_amdgcn_mfma_f32_16x16x32_bf16(af[mi], bfr[ni],
                                                              acc[mi][ni], 0, 0, 0);
    __syncthreads();  // reads done before next overwrite
  }

#pragma unroll
  for (int mi = 0; mi < 4; mi++) {
    const int row = m0 + wm * 64 + mi * 16 + ((lane >> 4) << 2);
#pragma unroll
    for (int ni = 0; ni < 4; ni++) {
      const int col = n0 + wn * 64 + ni * 16 + (lane & 15);
      const float bv = bias[col];
#pragma unroll
      for (int r = 0; r < 4; r++) {
        const size_t idx = (size_t)(row + r) * N + col;
        float v = acc[mi][ni][r] + bv;
        if (RESID) v += resid[idx];
        if (GELU) v = 0.5f * v * (1.0f + erff(v * 0.70710678118654752f));
        if (OUTB) outb[idx] = f2bf(v);
        else outf[idx] = v;
      }
    }
  }
}

// ---------------- embedding + LayerNorm (fused) ----------------
__global__ __launch_bounds__(256) void embed_ln(
    const int* __restrict__ ids, const float* __restrict__ wemb,
    const float* __restrict__ pemb, const float* __restrict__ g,
    const float* __restrict__ be, float* __restrict__ xo,
    unsigned short* __restrict__ xbo) {
  const int token = blockIdx.x;
  const int tid = threadIdx.x;
  const int id = ids[token];
  const int pos = token & (cS - 1);
  const float* wr = wemb + (size_t)id * cH;
  const float* pr = pemb + (size_t)pos * cH;
  float v[3];
#pragma unroll
  for (int i = 0; i < 3; i++) v[i] = wr[tid + i * 256] + pr[tid + i * 256];
  float s = v[0] + v[1] + v[2];
  float s2 = v[0] * v[0] + v[1] * v[1] + v[2] * v[2];
#pragma unroll
  for (int off = 32; off; off >>= 1) { s += __shfl_xor(s, off); s2 += __shfl_xor(s2, off); }
  __shared__ float sa[4], sb[4];
  if ((tid & 63) == 0) { sa[tid >> 6] = s; sb[tid >> 6] = s2; }
  __syncthreads();
  s = sa[0] + sa[1] + sa[2] + sa[3];
  s2 = sb[0] + sb[1] + sb[2] + sb[3];
  const float mean = s * (1.0f / cH);
  const float rstd = rsqrtf(s2 * (1.0f / cH) - mean * mean + 1e-12f);
  float* xr = xo + (size_t)token * cH;
  unsigned short* xbr = xbo + (size_t)token * cH;
#pragma unroll
  for (int i = 0; i < 3; i++) {
    const int c = tid + i * 256;
    const float nv = (v[i] - mean) * rstd * g[c] + be[c];
    xr[c] = nv;
    xbr[c] = f2bf(nv);
  }
}

// ---------------- in-place LayerNorm: x -> x (fp32) + xb (bf16) ----------------
__global__ __launch_bounds__(256) void ln_fused(
    float* __restrict__ x, const float* __restrict__ g,
    const float* __restrict__ be, unsigned short* __restrict__ xbo) {
  const int token = blockIdx.x;
  const int tid = threadIdx.x;
  float* row = x + (size_t)token * cH;
  float v[3];
#pragma unroll
  for (int i = 0; i < 3; i++) v[i] = row[tid + i * 256];
  float s = v[0] + v[1] + v[2];
  float s2 = v[0] * v[0] + v[1] * v[1] + v[2] * v[2];
#pragma unroll
  for (int off = 32; off; off >>= 1) { s += __shfl_xor(s, off); s2 += __shfl_xor(s2, off); }
  __shared__ float sa[4], sb[4];
  if ((tid & 63) == 0) { sa[tid >> 6] = s; sb[tid >> 6] = s2; }
  __syncthreads();
  s = sa[0] + sa[1] + sa[2] + sa[3];
  s2 = sb[0] + sb[1] + sb[2] + sb[3];
  const float mean = s * (1.0f / cH);
  const float rstd = rsqrtf(s2 * (1.0f / cH) - mean * mean + 1e-12f);
  unsigned short* xbr = xbo + (size_t)token * cH;
#pragma unroll
  for (int i = 0; i < 3; i++) {
    const int c = tid + i * 256;
    const float nv = (v[i] - mean) * rstd * g[c] + be[c];
    row[c] = nv;
    xbr[c] = f2bf(nv);
  }
}

// ---------------- flash attention, MFMA 16x16x32 bf16 ----------------
// Grid: B*NH*4 WGs; each WG = one (b,h) and a 128-query block; 4 waves x 32 queries.
// K-tile = 128 keys staged via global_load_lds (XOR-swizzled d-blocks);
// V staged transposed (Vt[d][key], swizzled key-blocks); P via per-wave LDS.
__global__ __launch_bounds__(256, 2) void attn_mfma(
    const unsigned short* __restrict__ qg, const unsigned short* __restrict__ kg,
    const unsigned short* __restrict__ vg, const int* __restrict__ amask,
    unsigned short* __restrict__ ctxb) {
  __shared__ __align__(16) unsigned short Ks[128 * 64];   // [key][physblk*8+j]
  __shared__ __align__(16) unsigned short Vt[64 * 128];   // [d][physblk*8 + key&7]
  __shared__ __align__(16) unsigned short Ps[4 * 32 * 136];
  __shared__ int lensh[4];

  const int tid = threadIdx.x, lane = tid & 63, wave = tid >> 6;
  const int quad = lane >> 4, col = lane & 15;
  const int wg = blockIdx.x;
  const int qb = wg & 3, h = (wg >> 2) % cNH, b = wg / (4 * cNH);
  const int q0 = qb * 128 + wave * 32;  // this wave's first query

  // sequence length (WG-uniform)
  const int* mrow = amask + b * cS;
  int c = mrow[tid] + mrow[tid + 256];
#pragma unroll
  for (int off = 32; off; off >>= 1) c += __shfl_xor(c, off);
  if (lane == 0) lensh[wave] = c;
  __syncthreads();
  const int len = lensh[0] + lensh[1] + lensh[2] + lensh[3];

  // resident Q fragments (A-operand), 32 queries x 64 d
  const unsigned short* qbase = qg + (size_t)(b * cS + q0) * cH + h * cDH;
  bh8_t qf[2][2];
#pragma unroll
  for (int mi = 0; mi < 2; mi++)
#pragma unroll
    for (int ks = 0; ks < 2; ks++)
      qf[mi][ks] = *(const bh8_t*)(qbase + (size_t)(mi * 16 + col) * cH + ks * 32 + quad * 8);

  float mr[2][4], lr[2][4];
  f4_t o[2][4] = {};
#pragma unroll
  for (int mi = 0; mi < 2; mi++)
#pragma unroll
    for (int r = 0; r < 4; r++) { mr[mi][r] = -3.0e38f; lr[mi][r] = 0.0f; }

  unsigned short* Pw = Ps + wave * (32 * 136);

  for (int k0 = 0; k0 < cS; k0 += 128) {
    if (k0 >= len) break;  // remaining tiles fully masked (len WG-uniform)
    __syncthreads();       // prior iter's Ks/Vt reads complete before restage
    const unsigned short* kb = kg + (size_t)(b * cS + k0) * cH + h * cDH;
    const unsigned short* vb = vg + (size_t)(b * cS + k0) * cH + h * cDH;
    // K: async16, LDS(key, physblk) <- global d-block (physblk ^ (key&7))
#pragma unroll
    for (int i = 0; i < 4; i++) {
      const int chunk = i * 256 + tid;
      const int key = chunk >> 3;
      const int ld = (chunk & 7) ^ (key & 7);
      async16(Ks + (size_t)(i * 256 + wave * 64) * 8, kb + (size_t)key * cH + ld * 8);
    }
    // V: manual transpose, Vt[d][pb*8 + key&7], pb = keyblk ^ (d&7) ^ (d>>3)
#pragma unroll
    for (int i = 0; i < 4; i++) {
      const int chunk = i * 256 + tid;
      const int key = chunk >> 3;
      const int ld = chunk & 7;
      const int bk = key >> 3;
      bh8_t vv = *(const bh8_t*)(vb + (size_t)key * cH + ld * 8);
      unsigned short vs[8];
      *(bh8_t*)vs = vv;
#pragma unroll
      for (int j = 0; j < 8; j++) {
        const int d = ld * 8 + j;
        const int pb = bk ^ j ^ ld;
        Vt[d * 128 + pb * 8 + (key & 7)] = vs[j];
      }
    }
    __syncthreads();  // staging visible (drains vmcnt+lgkmcnt)

    // S = Q K^T (32 q x 128 k per wave)
    f4_t s[2][8];
#pragma unroll
    for (int mi = 0; mi < 2; mi++)
#pragma unroll
      for (int n = 0; n < 8; n++) s[mi][n] = f4_t{0.f, 0.f, 0.f, 0.f};
#pragma unroll
    for (int n = 0; n < 8; n++) {
      const int r = n * 16 + col;  // key row
#pragma unroll
      for (int ks = 0; ks < 2; ks++) {
        const int phys = (ks * 4 + quad) ^ (col & 7);
        bh8_t kf = *(const bh8_t*)(Ks + (size_t)r * 64 + phys * 8);
        s[0][n] = __builtin_amdgcn_mfma_f32_16x16x32_bf16(qf[0][ks], kf, s[0][n], 0, 0, 0);
        s[1][n] = __builtin_amdgcn_mfma_f32_16x16x32_bf16(qf[1][ks], kf, s[1][n], 0, 0, 0);
      }
    }
    // scale + mask
#pragma unroll
    for (int n = 0; n < 8; n++) {
      const bool valid = (k0 + n * 16 + col) < len;
#pragma unroll
      for (int mi = 0; mi < 2; mi++)
#pragma unroll
        for (int r = 0; r < 4; r++)
          s[mi][n][r] = valid ? s[mi][n][r] * 0.125f : -3.0e38f;
    }
    // online softmax per query row (row lives on 16 lanes of one quad)
#pragma unroll
    for (int mi = 0; mi < 2; mi++)
#pragma unroll
      for (int r = 0; r < 4; r++) {
        float v = s[mi][0][r];
#pragma unroll
        for (int n = 1; n < 8; n++) v = fmaxf(v, s[mi][n][r]);
#pragma unroll
        for (int off = 1; off < 16; off <<= 1) v = fmaxf(v, __shfl_xor(v, off));
        const float nm = fmaxf(mr[mi][r], v);
        const float alpha = __expf(mr[mi][r] - nm);
        float rs = 0.0f;
#pragma unroll
        for (int n = 0; n < 8; n++) {
          const float p = __expf(s[mi][n][r] - nm);
          s[mi][n][r] = p;
          rs += p;
        }
#pragma unroll
        for (int off = 1; off < 16; off <<= 1) rs += __shfl_xor(rs, off);
        lr[mi][r] = lr[mi][r] * alpha + rs;
        mr[mi][r] = nm;
#pragma unroll
        for (int nd = 0; nd < 4; nd++) o[mi][nd][r] *= alpha;
      }
    // P -> LDS (C-layout write), then A-frag reads
#pragma unroll
    for (int mi = 0; mi < 2; mi++)
#pragma unroll
      for (int n = 0; n < 8; n++)
#pragma unroll
        for (int r = 0; r < 4; r++)
          Pw[(mi * 16 + quad * 4 + r) * 136 + n * 16 + col] = f2bf(s[mi][n][r]);
    __syncthreads();
    // O += P V
#pragma unroll
    for (int ks = 0; ks < 4; ks++) {
      bh8_t pf[2];
#pragma unroll
      for (int mi = 0; mi < 2; mi++)
        pf[mi] = *(const bh8_t*)(Pw + (size_t)(mi * 16 + col) * 136 + ks * 32 + quad * 8);
#pragma unroll
      for (int nd = 0; nd < 4; nd++) {
        const int d = nd * 16 + col;
        const int pb = (ks * 4 + quad) ^ (d & 7) ^ (d >> 3);
        bh8_t vf = *(const bh8_t*)(Vt + (size_t)d * 128 + pb * 8);
        o[0][nd] = __builtin_amdgcn_mfma_f32_16x16x32_bf16(pf[0], vf, o[0][nd], 0, 0, 0);
        o[1][nd] = __builtin_amdgcn_mfma_f32_16x16x32_bf16(pf[1], vf, o[1][nd], 0, 0, 0);
      }
    }
  }

  // epilogue: normalize and store ctx (bf16)
#pragma unroll
  for (int mi = 0; mi < 2; mi++)
#pragma unroll
    for (int r = 0; r < 4; r++) {
      const float inv = 1.0f / lr[mi][r];  // len >= 256 so lr > 0
      const int q = q0 + mi * 16 + quad * 4 + r;
      unsigned short* orow = ctxb + (size_t)(b * cS + q) * cH + h * cDH;
#pragma unroll
      for (int nd = 0; nd < 4; nd++) orow[nd * 16 + col] = f2bf(o[mi][nd][r] * inv);
    }
}

// ---------------- classifier head: emissions = x @ cls_w + cls_b ----------------
__global__ __launch_bounds__(256) void cls_head(
    const float* __restrict__ x, const float* __restrict__ w,
    const float* __restrict__ cb, float* __restrict__ em) {
  const int token = blockIdx.x * 4 + (threadIdx.x >> 6);
  const int lane = threadIdx.x & 63;
  const float* xr = x + (size_t)token * cH;
  float p[cT] = {};
  for (int k = lane; k < cH; k += 64) {
    const float xv = xr[k];
    const float* wr = w + k * cT;
#pragma unroll
    for (int t = 0; t < cT; t++) p[t] += xv * wr[t];
  }
#pragma unroll
  for (int t = 0; t < cT; t++) {
    float r = p[t];
#pragma unroll
    for (int off = 32; off; off >>= 1) r += __shfl_xor(r, off);
    if (lane == t) em[(size_t)token * cT + t] = r + cb[t];
  }
}

// ---------------- CRF NLL: one wave per sequence ----------------
__global__ __launch_bounds__(256) void crf(
    const float* __restrict__ em, const int* __restrict__ labels,
    const float* __restrict__ cstart, const float* __restrict__ cend,
    const float* __restrict__ ctrans, float* __restrict__ out) {
  const int b = blockIdx.x * 4 + (threadIdx.x >> 6);
  const int lane = threadIdx.x & 63;
  const int* lab = labels + b * cS;
  const float* eb = em + (size_t)b * cS * cT;

  float numpart = 0.0f;
  int cntpart = 0;
  for (int s = lane; s < cS; s += 64) {
    const int lb = lab[s];
    const bool valid = (s == 0) || (lb != -100);
    if (valid) {
      cntpart++;
      if (s > 0) numpart += ctrans[lab[s - 1] * cT + lb] + eb[s * cT + lb];
    }
  }
#pragma unroll
  for (int off = 32; off; off >>= 1) {
    numpart += __shfl_xor(numpart, off);
    cntpart += __shfl_xor(cntpart, off);
  }
  const int len = cntpart;
  const int l0 = lab[0];
  const float num = numpart + cstart[l0] + eb[l0] + cend[lab[len - 1]];

  float trj[cT];
  float alpha = -3.0e38f;
  if (lane < cT) {
#pragma unroll
    for (int i = 0; i < cT; i++) trj[i] = ctrans[i * cT + lane];
    alpha = cstart[lane] + eb[lane];
  } else {
#pragma unroll
    for (int i = 0; i < cT; i++) trj[i] = 0.0f;
  }
  for (int s = 1; s < cS; s++) {
    if (lab[s] == -100) break;
    const float ema = (lane < cT) ? eb[s * cT + lane] : 0.0f;
    float tv[cT], mx = -3.0e38f;
#pragma unroll
    for (int i = 0; i < cT; i++) {
      tv[i] = __shfl(alpha, i) + trj[i];
      mx = fmaxf(mx, tv[i]);
    }
    float ss = 0.0f;
#pragma unroll
    for (int i = 0; i < cT; i++) ss += __expf(tv[i] - mx);
    const float nxt = mx + __logf(ss) + ema;
    if (lane < cT) alpha = nxt;
  }
  float val = (lane < cT) ? alpha + cend[lane] : -3.0e38f;
  float mx = val;
#pragma unroll
  for (int off = 32; off; off >>= 1) mx = fmaxf(mx, __shfl_xor(mx, off));
  float se = __expf(val - mx);
#pragma unroll
  for (int off = 32; off; off >>= 1) se += __shfl_xor(se, off);
  if (lane == 0) atomicAdd(out, (mx + __logf(se) - num) * (1.0f / cB));
}

// ---------------- launch ----------------
extern "C" void kernel_launch(void* const* d_in, const int* in_sizes, int n_in,
                              void* d_out, int out_size, void* d_ws, size_t ws_size,
                              hipStream_t stream) {
  const float* word_emb = (const float*)d_in[0];
  const float* pos_emb = (const float*)d_in[1];
  const float* emb_ln_s = (const float*)d_in[2];
  const float* emb_ln_b = (const float*)d_in[3];
  const float* attn_qw = (const float*)d_in[4];
  const float* attn_qb = (const float*)d_in[5];
  const float* attn_kw = (const float*)d_in[6];
  const float* attn_kb = (const float*)d_in[7];
  const float* attn_vw = (const float*)d_in[8];
  const float* attn_vb = (const float*)d_in[9];
  const float* attn_ow = (const float*)d_in[10];
  const float* attn_ob = (const float*)d_in[11];
  const float* ln1_s = (const float*)d_in[12];
  const float* ln1_b = (const float*)d_in[13];
  const float* ffn_w1 = (const float*)d_in[14];
  const float* ffn_b1 = (const float*)d_in[15];
  const float* ffn_w2 = (const float*)d_in[16];
  const float* ffn_b2 = (const float*)d_in[17];
  const float* ln2_s = (const float*)d_in[18];
  const float* ln2_b = (const float*)d_in[19];
  const float* cls_w = (const float*)d_in[20];
  const float* cls_b = (const float*)d_in[21];
  const float* crf_start = (const float*)d_in[22];
  const float* crf_end = (const float*)d_in[23];
  const float* crf_trans = (const float*)d_in[24];
  const int* input_ids = (const int*)d_in[25];
  const int* amask = (const int*)d_in[26];
  const int* labels = (const int*)d_in[27];

  // ---- workspace layout (~191 MB total) ----
  char* ws = (char*)d_ws;
  size_t off = 0;
  auto alloc = [&](size_t bytes) -> void* {
    void* p = ws + off;
    off += (bytes + 255) & ~(size_t)255;
    return p;
  };
  constexpr size_t LW = 7077888;  // bf16 elems of one layer's transposed weights
  unsigned short* Wt = (unsigned short*)alloc(LW * 2);                  // 14.2 MB
  float* x = (float*)alloc((size_t)cM * cH * 4);                        // 50.3 MB
  unsigned short* xb = (unsigned short*)alloc((size_t)cM * cH * 2);     // 25.2 MB
  unsigned short* un = (unsigned short*)alloc((size_t)cM * cFF * 2);    // 100.7 MB
  unsigned short* qb = un;
  unsigned short* kbuf = un + (size_t)cM * cH;
  unsigned short* vbuf = un + (size_t)2 * cM * cH;
  unsigned short* ctx = un + (size_t)3 * cM * cH;
  unsigned short* hb = un;
  float* emis = (float*)alloc((size_t)cM * cT * 4);                     // 0.5 MB

  hipMemsetAsync(d_out, 0, sizeof(float) * out_size, stream);

  embed_ln<<<cM, 256, 0, stream>>>(input_ids, word_emb, pos_emb, emb_ln_s, emb_ln_b, x, xb);

  const dim3 tb(32, 8);
  for (int i = 0; i < cL; i++) {
    wtrans<<<dim3(cH / 32, cH / 32), tb, 0, stream>>>(attn_qw + (size_t)i * cH * cH, Wt + 0, cH, cH);
    wtrans<<<dim3(cH / 32, cH / 32), tb, 0, stream>>>(attn_kw + (size_t)i * cH * cH, Wt + 589824, cH, cH);
    wtrans<<<dim3(cH / 32, cH / 32), tb, 0, stream>>>(attn_vw + (size_t)i * cH * cH, Wt + 1179648, cH, cH);
    wtrans<<<dim3(cH / 32, cH / 32), tb, 0, stream>>>(attn_ow + (size_t)i * cH * cH, Wt + 1769472, cH, cH);
    wtrans<<<dim3(cFF / 32, cH / 32), tb, 0, stream>>>(ffn_w1 + (size_t)i * cH * cFF, Wt + 2359296, cH, cFF);
    wtrans<<<dim3(cH / 32, cFF / 32), tb, 0, stream>>>(ffn_w2 + (size_t)i * cFF * cH, Wt + 4718592, cFF, cH);

    gemm_bf16<false, false, true><<<dim3(cH / 128, cM / 128), 256, 0, stream>>>(
        xb, Wt + 0, attn_qb + i * cH, nullptr, nullptr, qb, cH, cH);
    gemm_bf16<false, false, true><<<dim3(cH / 128, cM / 128), 256, 0, stream>>>(
        xb, Wt + 589824, attn_kb + i * cH, nullptr, nullptr, kbuf, cH, cH);
    gemm_bf16<false, false, true><<<dim3(cH / 128, cM / 128), 256, 0, stream>>>(
        xb, Wt + 1179648, attn_vb + i * cH, nullptr, nullptr, vbuf, cH, cH);
    attn_mfma<<<cB * cNH * 4, 256, 0, stream>>>(qb, kbuf, vbuf, amask, ctx);
    gemm_bf16<true, false, false><<<dim3(cH / 128, cM / 128), 256, 0, stream>>>(
        ctx, Wt + 1769472, attn_ob + i * cH, x, x, nullptr, cH, cH);  // x += ctx@Wo+b
    ln_fused<<<cM, 256, 0, stream>>>(x, ln1_s + i * cH, ln1_b + i * cH, xb);
    gemm_bf16<false, true, true><<<dim3(cFF / 128, cM / 128), 256, 0, stream>>>(
        xb, Wt + 2359296, ffn_b1 + i * cFF, nullptr, nullptr, hb, cFF, cH);
    gemm_bf16<true, false, false><<<dim3(cH / 128, cM / 128), 256, 0, stream>>>(
        hb, Wt + 4718592, ffn_b2 + i * cH, x, x, nullptr, cH, cFF);   // x += h@W2+b
    ln_fused<<<cM, 256, 0, stream>>>(x, ln2_s + i * cH, ln2_b + i * cH, xb);
  }

  cls_head<<<cM / 4, 256, 0, stream>>>(x, cls_w, cls_b, emis);
  crf<<<cB / 4, 256, 0, stream>>>(emis, labels, crf_start, crf_end, crf_trans, (float*)d_out);
}

// Round 4
// 3810.976 us; speedup vs baseline: 7.8125x; 1.0098x over previous
//
#include <hip/hip_runtime.h>

// ---------------- problem constants ----------------
constexpr int cB = 32, cS = 512, cH = 768, cL = 6, cNH = 12, cFF = 3072, cT = 7;
constexpr int cM = cB * cS;     // 16384 tokens
constexpr int cDH = cH / cNH;   // 64
constexpr int cQS = 2304;       // fused qkv row stride

#define DEVI __device__ __forceinline__

typedef __attribute__((ext_vector_type(8))) short bh8_t;  // 8 bf16 (4 VGPRs)
typedef __attribute__((ext_vector_type(4))) float f4_t;   // MFMA accumulator

DEVI unsigned short f2bf(float f) {
  unsigned int u = __float_as_uint(f);
  return (unsigned short)((u + 0x7fffu + ((u >> 16) & 1u)) >> 16);
}
DEVI float bf2f(unsigned short h) { return __uint_as_float(((unsigned int)h) << 16); }

typedef __attribute__((address_space(1))) void* gas_t;
typedef __attribute__((address_space(3))) void* las_t;
DEVI void async16(void* lds, const void* g) {
  __builtin_amdgcn_global_load_lds((gas_t)g, (las_t)lds, 16, 0, 0);
}

// ---------------- batched weight transpose fp32(K,N) -> bf16(N,K) ----------------
// One launch per layer: blockIdx.z selects matrix {q,k,v,o,w1,w2}.
struct WtransArgs { const float* src[6]; };

__global__ void wtrans_all(WtransArgs args, unsigned short* __restrict__ out) {
  const int m = blockIdx.z;
  const int K = (m == 5) ? cFF : cH;
  const int N = (m == 4) ? cFF : cH;
  int n0, k0;
  if (m < 4) {
    if (blockIdx.x >= 24) return;
    n0 = blockIdx.x * 32; k0 = blockIdx.y * 32;
  } else if (m == 4) {
    n0 = blockIdx.x * 32; k0 = blockIdx.y * 32;   // N=3072: bx<96
  } else {
    k0 = blockIdx.x * 32; n0 = blockIdx.y * 32;   // K=3072: bx<96
  }
  const int woffs[6] = {0, 589824, 1179648, 1769472, 2359296, 4718592};
  const float* in = args.src[m];
  unsigned short* o = out + woffs[m];
  __shared__ float tile[32][33];
  const int tx = threadIdx.x, ty = threadIdx.y;  // block (32,8)
#pragma unroll
  for (int i = 0; i < 4; i++)
    tile[ty + i * 8][tx] = in[(size_t)(k0 + ty + i * 8) * N + n0 + tx];
  __syncthreads();
#pragma unroll
  for (int i = 0; i < 4; i++)
    o[(size_t)(n0 + ty + i * 8) * K + k0 + tx] = f2bf(tile[tx][ty + i * 8]);
}

__global__ void concat_bias(const float* __restrict__ qb, const float* __restrict__ kb,
                            const float* __restrict__ vb, float* __restrict__ out) {
  const int c = blockIdx.x * 256 + threadIdx.x;  // 0..2303
  if (c < cQS)
    out[c] = c < cH ? qb[c] : (c < 2 * cH ? kb[c - cH] : vb[c - 2 * cH]);
}

// ---------------- bf16 MFMA GEMM: C(M,N) = A(M,K) * Bt(N,K)^T ----------------
// 128x128 tile, BK=64, 256 threads (2x2 waves, each 64x64 via 4x4 mfma 16x16x32).
// K-chunks XOR-swizzled at staging (source permutation keeps global_load_lds
// dest lane-contiguous); fragment reads land on the 2-way bank floor.
// RESID path: outf may alias resid (same-thread same-index read-then-write).
template <bool RESID, bool GELU, bool OUTB>
__global__ __launch_bounds__(256) void gemm_bf16(
    const unsigned short* __restrict__ A, const unsigned short* __restrict__ Bt,
    const float* __restrict__ bias, const float* resid,
    float* outf, unsigned short* __restrict__ outb, int N, int K) {
  __shared__ __align__(16) unsigned short As[128 * 64];
  __shared__ __align__(16) unsigned short Bs[128 * 64];
  const int tid = threadIdx.x;
  const int lane = tid & 63;
  const int wave = tid >> 6;
  const int wm = wave >> 1, wn = wave & 1;
  const int quad = lane >> 4, col = lane & 15;
  const int m0 = blockIdx.y * 128;
  const int n0 = blockIdx.x * 128;

  f4_t acc[4][4] = {};

  // staging: chunk c = i*256+tid; row=c>>3, phys slot=c&7, global chunk = slot^(row&7)
  const int srow = tid >> 3;                    // 0..31 (i adds 32 per step)
  const int sgld = (tid & 7) ^ (srow & 7);      // (row&7) invariant under +32
  const unsigned short* gA = A + (size_t)(m0 + srow) * K + sgld * 8;
  const unsigned short* gB = Bt + (size_t)(n0 + srow) * K + sgld * 8;
  unsigned short* lA = As + tid * 8;
  unsigned short* lB = Bs + tid * 8;

  // loop-invariant fragment LDS offsets
  int offA[2][4], offB[2][4];
#pragma unroll
  for (int ks = 0; ks < 2; ks++) {
#pragma unroll
    for (int t = 0; t < 4; t++) {
      const int rA = wm * 64 + t * 16 + col;
      const int rB = wn * 64 + t * 16 + col;
      offA[ks][t] = rA * 64 + (((ks * 4 + quad) ^ (rA & 7)) << 3);
      offB[ks][t] = rB * 64 + (((ks * 4 + quad) ^ (rB & 7)) << 3);
    }
  }

  for (int k0 = 0; k0 < K; k0 += 64) {
#pragma unroll
    for (int i = 0; i < 4; i++)
      async16(lA + i * 2048, gA + k0 + (size_t)(i * 32) * K);
#pragma unroll
    for (int i = 0; i < 4; i++)
      async16(lB + i * 2048, gB + k0 + (size_t)(i * 32) * K);
    __syncthreads();  // drains vmcnt for global_load_lds before reads
#pragma unroll
    for (int ks = 0; ks < 2; ks++) {
      bh8_t af[4], bf[4];
#pragma unroll
      for (int t = 0; t < 4; t++) af[t] = *(const bh8_t*)(As + offA[ks][t]);
#pragma unroll
      for (int t = 0; t < 4; t++) bf[t] = *(const bh8_t*)(Bs + offB[ks][t]);
#pragma unroll
      for (int mi = 0; mi < 4; mi++)
#pragma unroll
        for (int ni = 0; ni < 4; ni++)
          acc[mi][ni] = __builtin_amdgcn_mfma_f32_16x16x32_bf16(af[mi], bf[ni],
                                                                acc[mi][ni], 0, 0, 0);
    }
    __syncthreads();  // reads done before next overwrite
  }

#pragma unroll
  for (int mi = 0; mi < 4; mi++) {
    const int row = m0 + wm * 64 + mi * 16 + (quad << 2);
#pragma unroll
    for (int ni = 0; ni < 4; ni++) {
      const int coln = n0 + wn * 64 + ni * 16 + col;
      const float bv = bias[coln];
#pragma unroll
      for (int r = 0; r < 4; r++) {
        const size_t idx = (size_t)(row + r) * N + coln;
        float v = acc[mi][ni][r] + bv;
        if (RESID) v += resid[idx];
        if (GELU) v = 0.5f * v * (1.0f + erff(v * 0.70710678118654752f));
        if (OUTB) outb[idx] = f2bf(v);
        else outf[idx] = v;
      }
    }
  }
}

// ---------------- embedding + LayerNorm (fused) ----------------
__global__ __launch_bounds__(256) void embed_ln(
    const int* __restrict__ ids, const float* __restrict__ wemb,
    const float* __restrict__ pemb, const float* __restrict__ g,
    const float* __restrict__ be, float* __restrict__ xo,
    unsigned short* __restrict__ xbo) {
  const int token = blockIdx.x;
  const int tid = threadIdx.x;
  const int id = ids[token];
  const int pos = token & (cS - 1);
  const float* wr = wemb + (size_t)id * cH;
  const float* pr = pemb + (size_t)pos * cH;
  float v[3];
#pragma unroll
  for (int i = 0; i < 3; i++) v[i] = wr[tid + i * 256] + pr[tid + i * 256];
  float s = v[0] + v[1] + v[2];
  float s2 = v[0] * v[0] + v[1] * v[1] + v[2] * v[2];
#pragma unroll
  for (int off = 32; off; off >>= 1) { s += __shfl_xor(s, off); s2 += __shfl_xor(s2, off); }
  __shared__ float sa[4], sb[4];
  if ((tid & 63) == 0) { sa[tid >> 6] = s; sb[tid >> 6] = s2; }
  __syncthreads();
  s = sa[0] + sa[1] + sa[2] + sa[3];
  s2 = sb[0] + sb[1] + sb[2] + sb[3];
  const float mean = s * (1.0f / cH);
  const float rstd = rsqrtf(s2 * (1.0f / cH) - mean * mean + 1e-12f);
  float* xr = xo + (size_t)token * cH;
  unsigned short* xbr = xbo + (size_t)token * cH;
#pragma unroll
  for (int i = 0; i < 3; i++) {
    const int c = tid + i * 256;
    const float nv = (v[i] - mean) * rstd * g[c] + be[c];
    xr[c] = nv;
    xbr[c] = f2bf(nv);
  }
}

// ---------------- in-place LayerNorm: x -> x (fp32) + xb (bf16) ----------------
__global__ __launch_bounds__(256) void ln_fused(
    float* __restrict__ x, const float* __restrict__ g,
    const float* __restrict__ be, unsigned short* __restrict__ xbo) {
  const int token = blockIdx.x;
  const int tid = threadIdx.x;
  float* row = x + (size_t)token * cH;
  float v[3];
#pragma unroll
  for (int i = 0; i < 3; i++) v[i] = row[tid + i * 256];
  float s = v[0] + v[1] + v[2];
  float s2 = v[0] * v[0] + v[1] * v[1] + v[2] * v[2];
#pragma unroll
  for (int off = 32; off; off >>= 1) { s += __shfl_xor(s, off); s2 += __shfl_xor(s2, off); }
  __shared__ float sa[4], sb[4];
  if ((tid & 63) == 0) { sa[tid >> 6] = s; sb[tid >> 6] = s2; }
  __syncthreads();
  s = sa[0] + sa[1] + sa[2] + sa[3];
  s2 = sb[0] + sb[1] + sb[2] + sb[3];
  const float mean = s * (1.0f / cH);
  const float rstd = rsqrtf(s2 * (1.0f / cH) - mean * mean + 1e-12f);
  unsigned short* xbr = xbo + (size_t)token * cH;
#pragma unroll
  for (int i = 0; i < 3; i++) {
    const int c = tid + i * 256;
    const float nv = (v[i] - mean) * rstd * g[c] + be[c];
    row[c] = nv;
    xbr[c] = f2bf(nv);
  }
}

// ---------------- flash attention, MFMA 16x16x32 bf16 (fused qkv input) -------
__global__ __launch_bounds__(256, 2) void attn_mfma(
    const unsigned short* __restrict__ qkv, const int* __restrict__ amask,
    unsigned short* __restrict__ ctxb) {
  __shared__ __align__(16) unsigned short Ks[128 * 64];   // [key][physblk*8+j]
  __shared__ __align__(16) unsigned short Vt[64 * 128];   // [d][physblk*8 + key&7]
  __shared__ __align__(16) unsigned short Ps[4 * 32 * 136];
  __shared__ int lensh[4];

  const int tid = threadIdx.x, lane = tid & 63, wave = tid >> 6;
  const int quad = lane >> 4, col = lane & 15;
  const int wg = blockIdx.x;
  const int qb = wg & 3, h = (wg >> 2) % cNH, b = wg / (4 * cNH);
  const int q0 = qb * 128 + wave * 32;  // this wave's first query

  const unsigned short* qg = qkv;
  const unsigned short* kg = qkv + cH;
  const unsigned short* vg = qkv + 2 * cH;

  // sequence length (WG-uniform)
  const int* mrow = amask + b * cS;
  int c = mrow[tid] + mrow[tid + 256];
#pragma unroll
  for (int off = 32; off; off >>= 1) c += __shfl_xor(c, off);
  if (lane == 0) lensh[wave] = c;
  __syncthreads();
  const int len = lensh[0] + lensh[1] + lensh[2] + lensh[3];

  // resident Q fragments (A-operand), 32 queries x 64 d
  const unsigned short* qbase = qg + (size_t)(b * cS + q0) * cQS + h * cDH;
  bh8_t qf[2][2];
#pragma unroll
  for (int mi = 0; mi < 2; mi++)
#pragma unroll
    for (int ks = 0; ks < 2; ks++)
      qf[mi][ks] = *(const bh8_t*)(qbase + (size_t)(mi * 16 + col) * cQS + ks * 32 + quad * 8);

  float mr[2][4], lr[2][4];
  f4_t o[2][4] = {};
#pragma unroll
  for (int mi = 0; mi < 2; mi++)
#pragma unroll
    for (int r = 0; r < 4; r++) { mr[mi][r] = -3.0e38f; lr[mi][r] = 0.0f; }

  unsigned short* Pw = Ps + wave * (32 * 136);

  for (int k0 = 0; k0 < cS; k0 += 128) {
    if (k0 >= len) break;  // remaining tiles fully masked (len WG-uniform)
    __syncthreads();       // prior iter's Ks/Vt reads complete before restage
    const unsigned short* kb = kg + (size_t)(b * cS + k0) * cQS + h * cDH;
    const unsigned short* vb = vg + (size_t)(b * cS + k0) * cQS + h * cDH;
    // K: async16, LDS(key, physblk) <- global d-block (physblk ^ (key&7))
#pragma unroll
    for (int i = 0; i < 4; i++) {
      const int chunk = i * 256 + tid;
      const int key = chunk >> 3;
      const int ld = (chunk & 7) ^ (key & 7);
      async16(Ks + (size_t)(i * 256 + wave * 64) * 8, kb + (size_t)key * cQS + ld * 8);
    }
    // V: manual transpose, Vt[d][pb*8 + key&7], pb = keyblk ^ (d&7) ^ (d>>3)
#pragma unroll
    for (int i = 0; i < 4; i++) {
      const int chunk = i * 256 + tid;
      const int key = chunk >> 3;
      const int ld = chunk & 7;
      const int bk = key >> 3;
      bh8_t vv = *(const bh8_t*)(vb + (size_t)key * cQS + ld * 8);
      unsigned short vs[8];
      *(bh8_t*)vs = vv;
#pragma unroll
      for (int j = 0; j < 8; j++) {
        const int d = ld * 8 + j;
        const int pb = bk ^ j ^ ld;
        Vt[d * 128 + pb * 8 + (key & 7)] = vs[j];
      }
    }
    __syncthreads();  // staging visible (drains vmcnt+lgkmcnt)

    // S = Q K^T (32 q x 128 k per wave)
    f4_t s[2][8];
#pragma unroll
    for (int mi = 0; mi < 2; mi++)
#pragma unroll
      for (int n = 0; n < 8; n++) s[mi][n] = f4_t{0.f, 0.f, 0.f, 0.f};
#pragma unroll
    for (int n = 0; n < 8; n++) {
      const int r = n * 16 + col;  // key row
#pragma unroll
      for (int ks = 0; ks < 2; ks++) {
        const int phys = (ks * 4 + quad) ^ (col & 7);
        bh8_t kf = *(const bh8_t*)(Ks + (size_t)r * 64 + phys * 8);
        s[0][n] = __builtin_amdgcn_mfma_f32_16x16x32_bf16(qf[0][ks], kf, s[0][n], 0, 0, 0);
        s[1][n] = __builtin_amdgcn_mfma_f32_16x16x32_bf16(qf[1][ks], kf, s[1][n], 0, 0, 0);
      }
    }
    // scale + mask
#pragma unroll
    for (int n = 0; n < 8; n++) {
      const bool valid = (k0 + n * 16 + col) < len;
#pragma unroll
      for (int mi = 0; mi < 2; mi++)
#pragma unroll
        for (int r = 0; r < 4; r++)
          s[mi][n][r] = valid ? s[mi][n][r] * 0.125f : -3.0e38f;
    }
    // online softmax per query row (row lives on 16 lanes of one quad)
#pragma unroll
    for (int mi = 0; mi < 2; mi++)
#pragma unroll
      for (int r = 0; r < 4; r++) {
        float v = s[mi][0][r];
#pragma unroll
        for (int n = 1; n < 8; n++) v = fmaxf(v, s[mi][n][r]);
#pragma unroll
        for (int off = 1; off < 16; off <<= 1) v = fmaxf(v, __shfl_xor(v, off));
        const float nm = fmaxf(mr[mi][r], v);
        const float alpha = __expf(mr[mi][r] - nm);
        float rs = 0.0f;
#pragma unroll
        for (int n = 0; n < 8; n++) {
          const float p = __expf(s[mi][n][r] - nm);
          s[mi][n][r] = p;
          rs += p;
        }
#pragma unroll
        for (int off = 1; off < 16; off <<= 1) rs += __shfl_xor(rs, off);
        lr[mi][r] = lr[mi][r] * alpha + rs;
        mr[mi][r] = nm;
#pragma unroll
        for (int nd = 0; nd < 4; nd++) o[mi][nd][r] *= alpha;
      }
    // P -> LDS (C-layout write), then A-frag reads
#pragma unroll
    for (int mi = 0; mi < 2; mi++)
#pragma unroll
      for (int n = 0; n < 8; n++)
#pragma unroll
        for (int r = 0; r < 4; r++)
          Pw[(mi * 16 + quad * 4 + r) * 136 + n * 16 + col] = f2bf(s[mi][n][r]);
    __syncthreads();
    // O += P V
#pragma unroll
    for (int ks = 0; ks < 4; ks++) {
      bh8_t pf[2];
#pragma unroll
      for (int mi = 0; mi < 2; mi++)
        pf[mi] = *(const bh8_t*)(Pw + (size_t)(mi * 16 + col) * 136 + ks * 32 + quad * 8);
#pragma unroll
      for (int nd = 0; nd < 4; nd++) {
        const int d = nd * 16 + col;
        const int pb = (ks * 4 + quad) ^ (d & 7) ^ (d >> 3);
        bh8_t vf = *(const bh8_t*)(Vt + (size_t)d * 128 + pb * 8);
        o[0][nd] = __builtin_amdgcn_mfma_f32_16x16x32_bf16(pf[0], vf, o[0][nd], 0, 0, 0);
        o[1][nd] = __builtin_amdgcn_mfma_f32_16x16x32_bf16(pf[1], vf, o[1][nd], 0, 0, 0);
      }
    }
  }

  // epilogue: normalize and store ctx (bf16)
#pragma unroll
  for (int mi = 0; mi < 2; mi++)
#pragma unroll
    for (int r = 0; r < 4; r++) {
      const float inv = 1.0f / lr[mi][r];  // len >= 256 so lr > 0
      const int q = q0 + mi * 16 + quad * 4 + r;
      unsigned short* orow = ctxb + (size_t)(b * cS + q) * cH + h * cDH;
#pragma unroll
      for (int nd = 0; nd < 4; nd++) orow[nd * 16 + col] = f2bf(o[mi][nd][r] * inv);
    }
}

// ---------------- classifier head: emissions = x @ cls_w + cls_b ----------------
__global__ __launch_bounds__(256) void cls_head(
    const float* __restrict__ x, const float* __restrict__ w,
    const float* __restrict__ cb, float* __restrict__ em) {
  const int token = blockIdx.x * 4 + (threadIdx.x >> 6);
  const int lane = threadIdx.x & 63;
  const float* xr = x + (size_t)token * cH;
  float p[cT] = {};
  for (int k = lane; k < cH; k += 64) {
    const float xv = xr[k];
    const float* wr = w + k * cT;
#pragma unroll
    for (int t = 0; t < cT; t++) p[t] += xv * wr[t];
  }
#pragma unroll
  for (int t = 0; t < cT; t++) {
    float r = p[t];
#pragma unroll
    for (int off = 32; off; off >>= 1) r += __shfl_xor(r, off);
    if (lane == t) em[(size_t)token * cT + t] = r + cb[t];
  }
}

// ---------------- CRF NLL: chunked log-semiring scan, one block per sequence ----
// 16 waves x 32-step chunks; 7x7 matrices on lanes (i,j)=lane/7,lane%7;
// ordered 4-level tree combine; alpha0 applied at the end.
__global__ __launch_bounds__(1024) void crf(
    const float* __restrict__ em, const int* __restrict__ labels,
    const float* __restrict__ cstart, const float* __restrict__ cend,
    const float* __restrict__ ctrans, float* __restrict__ out) {
  const int b = blockIdx.x;
  const int tid = threadIdx.x;
  const int wave = tid >> 6, lane = tid & 63;
  const int* lab = labels + b * cS;
  const float* eb = em + (size_t)b * cS * cT;

  __shared__ float mats[16][49];
  __shared__ float mbuf[8][49];
  __shared__ int slen;
  __shared__ float snum;
  if (tid == 0) { slen = 0; snum = 0.0f; }
  __syncthreads();

  // length: mask is a contiguous prefix; s=0 always valid
  if (tid < cS) {
    const int valid = (tid == 0) || (lab[tid] != -100);
    const unsigned long long bal = __ballot(valid);
    if (lane == 0) atomicAdd(&slen, __popcll(bal));
  }
  __syncthreads();
  const int len = slen;

  // numerator: distributed over all 1024 threads
  {
    float np = 0.0f;
    if (tid >= 1 && tid < len)
      np = ctrans[lab[tid - 1] * cT + lab[tid]] + eb[tid * cT + lab[tid]];
#pragma unroll
    for (int off = 32; off; off >>= 1) np += __shfl_xor(np, off);
    if (lane == 0) atomicAdd(&snum, np);
  }

  // chunk product: wave w composes steps s in [1+32w, min(33+32w, len))
  const int ii = (lane < 49) ? lane / 7 : 0;
  const int jj = (lane < 49) ? lane % 7 : 0;
  const int i7 = ii * 7;
  float trk[cT];
#pragma unroll
  for (int k = 0; k < cT; k++) trk[k] = ctrans[k * cT + jj];

  float Nij = (ii == jj) ? 0.0f : -1.0e30f;  // log-semiring identity
  const int s_beg = 1 + 32 * wave;
  const int s_end = min(s_beg + 32, len);
  for (int s = s_beg; s < s_end; s++) {
    const float ej = eb[s * cT + jj];
    float v[cT];
#pragma unroll
    for (int k = 0; k < cT; k++) v[k] = __shfl(Nij, i7 + k) + trk[k];
    float mx = v[0];
#pragma unroll
    for (int k = 1; k < cT; k++) mx = fmaxf(mx, v[k]);
    float ss = 0.0f;
#pragma unroll
    for (int k = 0; k < cT; k++) ss += __expf(v[k] - mx);
    Nij = mx + __logf(ss) + ej;
  }
  if (lane < 49) mats[wave][lane] = Nij;
  __syncthreads();

  // ordered tree combine: (A ⊗ B)[i][j] = lse_k(A[i][k] + B[k][j])
  auto compose = [&](const float* Am, const float* Bm) -> float {
    float v[cT];
#pragma unroll
    for (int k = 0; k < cT; k++) v[k] = Am[i7 + k] + Bm[k * 7 + jj];
    float mx = v[0];
#pragma unroll
    for (int k = 1; k < cT; k++) mx = fmaxf(mx, v[k]);
    float ss = 0.0f;
#pragma unroll
    for (int k = 0; k < cT; k++) ss += __expf(v[k] - mx);
    return mx + __logf(ss);
  };
  if (wave < 8 && lane < 49) mbuf[wave][lane] = compose(mats[2 * wave], mats[2 * wave + 1]);
  __syncthreads();
  if (wave < 4 && lane < 49) mats[wave][lane] = compose(mbuf[2 * wave], mbuf[2 * wave + 1]);
  __syncthreads();
  if (wave < 2 && lane < 49) mbuf[wave][lane] = compose(mats[2 * wave], mats[2 * wave + 1]);
  __syncthreads();

  if (wave == 0) {
    float Mij = compose(mbuf[0], mbuf[1]);          // lanes >=49 compute garbage, unused
    const float a0 = cstart[ii] + eb[ii];           // alpha0[i]
    const float t = a0 + Mij;
    // alpha_final[j] = lse_i t(i,j): gather column j on lane j
    float av[cT];
#pragma unroll
    for (int k = 0; k < cT; k++) av[k] = __shfl(t, k * 7 + lane);  // valid for lane<7
    float mx = av[0];
#pragma unroll
    for (int k = 1; k < cT; k++) mx = fmaxf(mx, av[k]);
    float ss = 0.0f;
#pragma unroll
    for (int k = 0; k < cT; k++) ss += __expf(av[k] - mx);
    const float afin = mx + __logf(ss) + ((lane < cT) ? cend[lane] : 0.0f);
    // denom = lse_j (lanes 0..6)
    float dv[cT];
#pragma unroll
    for (int k = 0; k < cT; k++) dv[k] = __shfl(afin, k);
    float dmx = dv[0];
#pragma unroll
    for (int k = 1; k < cT; k++) dmx = fmaxf(dmx, dv[k]);
    float dss = 0.0f;
#pragma unroll
    for (int k = 0; k < cT; k++) dss += __expf(dv[k] - dmx);
    const float denom = dmx + __logf(dss);
    if (lane == 0) {
      const int l0 = lab[0];
      const float num = snum + cstart[l0] + eb[l0] + cend[lab[len - 1]];
      atomicAdd(out, (denom - num) * (1.0f / cB));
    }
  }
}

// ---------------- launch ----------------
extern "C" void kernel_launch(void* const* d_in, const int* in_sizes, int n_in,
                              void* d_out, int out_size, void* d_ws, size_t ws_size,
                              hipStream_t stream) {
  const float* word_emb = (const float*)d_in[0];
  const float* pos_emb = (const float*)d_in[1];
  const float* emb_ln_s = (const float*)d_in[2];
  const float* emb_ln_b = (const float*)d_in[3];
  const float* attn_qw = (const float*)d_in[4];
  const float* attn_qb = (const float*)d_in[5];
  const float* attn_kw = (const float*)d_in[6];
  const float* attn_kb = (const float*)d_in[7];
  const float* attn_vw = (const float*)d_in[8];
  const float* attn_vb = (const float*)d_in[9];
  const float* attn_ow = (const float*)d_in[10];
  const float* attn_ob = (const float*)d_in[11];
  const float* ln1_s = (const float*)d_in[12];
  const float* ln1_b = (const float*)d_in[13];
  const float* ffn_w1 = (const float*)d_in[14];
  const float* ffn_b1 = (const float*)d_in[15];
  const float* ffn_w2 = (const float*)d_in[16];
  const float* ffn_b2 = (const float*)d_in[17];
  const float* ln2_s = (const float*)d_in[18];
  const float* ln2_b = (const float*)d_in[19];
  const float* cls_w = (const float*)d_in[20];
  const float* cls_b = (const float*)d_in[21];
  const float* crf_start = (const float*)d_in[22];
  const float* crf_end = (const float*)d_in[23];
  const float* crf_trans = (const float*)d_in[24];
  const int* input_ids = (const int*)d_in[25];
  const int* amask = (const int*)d_in[26];
  const int* labels = (const int*)d_in[27];

  // ---- workspace layout (~191 MB total) ----
  char* ws = (char*)d_ws;
  size_t off = 0;
  auto alloc = [&](size_t bytes) -> void* {
    void* p = ws + off;
    off += (bytes + 255) & ~(size_t)255;
    return p;
  };
  constexpr size_t LW = 7077888;  // bf16 elems of one layer's transposed weights
  unsigned short* Wt = (unsigned short*)alloc(LW * 2);                  // 14.2 MB
  float* qkvb = (float*)alloc(cQS * 4);                                 // 9 KB
  float* x = (float*)alloc((size_t)cM * cH * 4);                        // 50.3 MB
  unsigned short* xb = (unsigned short*)alloc((size_t)cM * cH * 2);     // 25.2 MB
  unsigned short* un = (unsigned short*)alloc((size_t)cM * cFF * 2);    // 100.7 MB
  unsigned short* qkv = un;                       // cM x 2304 (attn phase)
  unsigned short* ctx = un + (size_t)cM * cQS;    // cM x 768
  unsigned short* hb = un;                        // cM x 3072 (FFN phase)
  float* emis = (float*)alloc((size_t)cM * cT * 4);                     // 0.5 MB

  hipMemsetAsync(d_out, 0, sizeof(float) * out_size, stream);

  embed_ln<<<cM, 256, 0, stream>>>(input_ids, word_emb, pos_emb, emb_ln_s, emb_ln_b, x, xb);

  for (int i = 0; i < cL; i++) {
    WtransArgs wa;
    wa.src[0] = attn_qw + (size_t)i * cH * cH;
    wa.src[1] = attn_kw + (size_t)i * cH * cH;
    wa.src[2] = attn_vw + (size_t)i * cH * cH;
    wa.src[3] = attn_ow + (size_t)i * cH * cH;
    wa.src[4] = ffn_w1 + (size_t)i * cH * cFF;
    wa.src[5] = ffn_w2 + (size_t)i * cFF * cH;
    wtrans_all<<<dim3(96, 24, 6), dim3(32, 8), 0, stream>>>(wa, Wt);
    concat_bias<<<9, 256, 0, stream>>>(attn_qb + i * cH, attn_kb + i * cH,
                                       attn_vb + i * cH, qkvb);

    gemm_bf16<false, false, true><<<dim3(cQS / 128, cM / 128), 256, 0, stream>>>(
        xb, Wt, qkvb, nullptr, nullptr, qkv, cQS, cH);
    attn_mfma<<<cB * cNH * 4, 256, 0, stream>>>(qkv, amask, ctx);
    gemm_bf16<true, false, false><<<dim3(cH / 128, cM / 128), 256, 0, stream>>>(
        ctx, Wt + 1769472, attn_ob + i * cH, x, x, nullptr, cH, cH);  // x += ctx@Wo+b
    ln_fused<<<cM, 256, 0, stream>>>(x, ln1_s + i * cH, ln1_b + i * cH, xb);
    gemm_bf16<false, true, true><<<dim3(cFF / 128, cM / 128), 256, 0, stream>>>(
        xb, Wt + 2359296, ffn_b1 + i * cFF, nullptr, nullptr, hb, cFF, cH);
    gemm_bf16<true, false, false><<<dim3(cH / 128, cM / 128), 256, 0, stream>>>(
        hb, Wt + 4718592, ffn_b2 + i * cH, x, x, nullptr, cH, cFF);   // x += h@W2+b
    ln_fused<<<cM, 256, 0, stream>>>(x, ln2_s + i * cH, ln2_b + i * cH, xb);
  }

  cls_head<<<cM / 4, 256, 0, stream>>>(x, cls_w, cls_b, emis);
  crf<<<cB, 1024, 0, stream>>>(emis, labels, crf_start, crf_end, crf_trans, (float*)d_out);
}

// Round 5
// 3665.359 us; speedup vs baseline: 8.1229x; 1.0397x over previous
//
#include <hip/hip_runtime.h>

// ---------------- problem constants ----------------
constexpr int cB = 32, cS = 512, cH = 768, cL = 6, cNH = 12, cFF = 3072, cT = 7;
constexpr int cM = cB * cS;     // 16384 tokens
constexpr int cDH = cH / cNH;   // 64
constexpr int cQS = 2304;       // fused qkv row stride

#define DEVI __device__ __forceinline__

typedef __attribute__((ext_vector_type(8))) short bh8_t;          // 8 bf16 (4 VGPRs)
typedef __attribute__((ext_vector_type(4))) float f4_t;           // MFMA accumulator
typedef __attribute__((ext_vector_type(4))) unsigned short us4_t; // 4 bf16 (8B store)

DEVI unsigned short f2bf(float f) {
  unsigned int u = __float_as_uint(f);
  return (unsigned short)((u + 0x7fffu + ((u >> 16) & 1u)) >> 16);
}
DEVI float bf2f(unsigned short h) { return __uint_as_float(((unsigned int)h) << 16); }

// Abramowitz-Stegun 7.1.26, |abs err| < 1.5e-7 — far below the 16.48 threshold.
DEVI float fast_erff(float x) {
  const float a = fabsf(x);
  const float t = 1.0f / (1.0f + 0.3275911f * a);
  const float y = 1.0f - (((((1.061405429f * t - 1.453152027f) * t) + 1.421413741f) * t
                            - 0.284496736f) * t + 0.254829592f) * t * __expf(-a * a);
  return copysignf(y, x);
}

typedef __attribute__((address_space(1))) void* gas_t;
typedef __attribute__((address_space(3))) void* las_t;
DEVI void async16(void* lds, const void* g) {
  __builtin_amdgcn_global_load_lds((gas_t)g, (las_t)lds, 16, 0, 0);
}

// ---------------- batched weight transpose fp32(K,N) -> bf16(N,K) ----------------
struct WtransArgs { const float* src[6]; };

__global__ void wtrans_all(WtransArgs args, unsigned short* __restrict__ out) {
  const int m = blockIdx.z;
  const int K = (m == 5) ? cFF : cH;
  const int N = (m == 4) ? cFF : cH;
  int n0, k0;
  if (m < 4) {
    if (blockIdx.x >= 24) return;
    n0 = blockIdx.x * 32; k0 = blockIdx.y * 32;
  } else if (m == 4) {
    n0 = blockIdx.x * 32; k0 = blockIdx.y * 32;   // N=3072: bx<96
  } else {
    k0 = blockIdx.x * 32; n0 = blockIdx.y * 32;   // K=3072: bx<96
  }
  const int woffs[6] = {0, 589824, 1179648, 1769472, 2359296, 4718592};
  const float* in = args.src[m];
  unsigned short* o = out + woffs[m];
  __shared__ float tile[32][33];
  const int tx = threadIdx.x, ty = threadIdx.y;  // block (32,8)
#pragma unroll
  for (int i = 0; i < 4; i++)
    tile[ty + i * 8][tx] = in[(size_t)(k0 + ty + i * 8) * N + n0 + tx];
  __syncthreads();
#pragma unroll
  for (int i = 0; i < 4; i++)
    o[(size_t)(n0 + ty + i * 8) * K + k0 + tx] = f2bf(tile[tx][ty + i * 8]);
}

__global__ void concat_bias(const float* __restrict__ qb, const float* __restrict__ kb,
                            const float* __restrict__ vb, float* __restrict__ out) {
  const int c = blockIdx.x * 256 + threadIdx.x;  // 0..2303
  if (c < cQS)
    out[c] = c < cH ? qb[c] : (c < 2 * cH ? kb[c - cH] : vb[c - 2 * cH]);
}

// ---------------- bf16 MFMA GEMM: C(M,N) = A(M,K) * Bt(N,K)^T ----------------
// 128x128 tile, BK=32 (16 KB LDS — occupancy is the binding constraint, R4 lesson).
// LDS chunks XOR-swizzled (phys = q ^ ((row>>1)&3)) via SOURCE permutation so the
// global_load_lds dest stays lane-contiguous; fragment ds_read_b128 land on the
// free 2-way bank floor. MFMA operands SWAPPED -> C^T fragments: each lane holds
// 4 consecutive output columns -> vectorized epilogue (dwordx2 bf16 / dwordx4 f32).
// RESID path: outf may alias resid (same-thread same-index read-then-write).
template <bool RESID, bool GELU, bool OUTB>
__global__ __launch_bounds__(256) void gemm_bf16(
    const unsigned short* __restrict__ A, const unsigned short* __restrict__ Bt,
    const float* __restrict__ bias, const float* resid,
    float* outf, unsigned short* __restrict__ outb, int N, int K) {
  __shared__ __align__(16) unsigned short As[128 * 32];
  __shared__ __align__(16) unsigned short Bs[128 * 32];
  const int tid = threadIdx.x;
  const int lane = tid & 63;
  const int wave = tid >> 6;
  const int wm = wave >> 1, wn = wave & 1;
  const int quad = lane >> 4, col = lane & 15;
  const int m0 = blockIdx.y * 128;
  const int n0 = blockIdx.x * 128;

  f4_t acc[4][4] = {};

  // staging: dest chunk = tid (row=tid>>2, phys=tid&3); source chunk = phys ^ ((row>>1)&3)
  const int rA = tid >> 2;
  const int cXor = ((tid & 3) ^ ((tid >> 3) & 3)) << 3;
  const unsigned short* gA = A + (size_t)(m0 + rA) * K + cXor;
  const unsigned short* gB = Bt + (size_t)(n0 + rA) * K + cXor;
  unsigned short* lA0 = As + wave * 512;
  unsigned short* lA1 = As + 2048 + wave * 512;
  unsigned short* lB0 = Bs + wave * 512;
  unsigned short* lB1 = Bs + 2048 + wave * 512;

  // fragment read: row-dependent phys chunk = quad ^ ((row>>1)&3); for rows
  // t*16+col the term ((row>>1)&3) == ((col>>1)&3) — t-invariant.
  const int physq = quad ^ ((col >> 1) & 3);
  const unsigned short* fA[4];
  const unsigned short* fB[4];
#pragma unroll
  for (int t = 0; t < 4; t++) {
    fA[t] = As + (size_t)(wm * 64 + t * 16 + col) * 32 + physq * 8;
    fB[t] = Bs + (size_t)(wn * 64 + t * 16 + col) * 32 + physq * 8;
  }

  for (int k0 = 0; k0 < K; k0 += 32) {
    async16(lA0, gA + k0);
    async16(lA1, gA + (size_t)64 * K + k0);
    async16(lB0, gB + k0);
    async16(lB1, gB + (size_t)64 * K + k0);
    __syncthreads();  // drains vmcnt for global_load_lds before reads
    bh8_t af[4], bf[4];
#pragma unroll
    for (int t = 0; t < 4; t++) af[t] = *(const bh8_t*)fA[t];
#pragma unroll
    for (int t = 0; t < 4; t++) bf[t] = *(const bh8_t*)fB[t];
#pragma unroll
    for (int mi = 0; mi < 4; mi++)
#pragma unroll
      for (int ni = 0; ni < 4; ni++)   // swapped operands -> C^T fragment layout
        acc[mi][ni] = __builtin_amdgcn_mfma_f32_16x16x32_bf16(bf[ni], af[mi],
                                                              acc[mi][ni], 0, 0, 0);
    __syncthreads();  // reads done before next overwrite
  }

  // epilogue: lane holds rows m = mi*16+col, cols n = ni*16 + quad*4 + (0..3)
#pragma unroll
  for (int mi = 0; mi < 4; mi++) {
    const size_t rowbase = (size_t)(m0 + wm * 64 + mi * 16 + col) * N;
#pragma unroll
    for (int ni = 0; ni < 4; ni++) {
      const int cb = n0 + wn * 64 + ni * 16 + quad * 4;
      f4_t v = acc[mi][ni] + *(const f4_t*)(bias + cb);
      if (RESID) v += *(const f4_t*)(resid + rowbase + cb);
      if (GELU) {
#pragma unroll
        for (int r = 0; r < 4; r++)
          v[r] = 0.5f * v[r] * (1.0f + fast_erff(v[r] * 0.70710678118654752f));
      }
      if (OUTB) {
        us4_t u;
#pragma unroll
        for (int r = 0; r < 4; r++) u[r] = f2bf(v[r]);
        *(us4_t*)(outb + rowbase + cb) = u;
      } else {
        *(f4_t*)(outf + rowbase + cb) = v;
      }
    }
  }
}

// ---------------- embedding + LayerNorm (fused) ----------------
__global__ __launch_bounds__(256) void embed_ln(
    const int* __restrict__ ids, const float* __restrict__ wemb,
    const float* __restrict__ pemb, const float* __restrict__ g,
    const float* __restrict__ be, float* __restrict__ xo,
    unsigned short* __restrict__ xbo) {
  const int token = blockIdx.x;
  const int tid = threadIdx.x;
  const int id = ids[token];
  const int pos = token & (cS - 1);
  const float* wr = wemb + (size_t)id * cH;
  const float* pr = pemb + (size_t)pos * cH;
  float v[3];
#pragma unroll
  for (int i = 0; i < 3; i++) v[i] = wr[tid + i * 256] + pr[tid + i * 256];
  float s = v[0] + v[1] + v[2];
  float s2 = v[0] * v[0] + v[1] * v[1] + v[2] * v[2];
#pragma unroll
  for (int off = 32; off; off >>= 1) { s += __shfl_xor(s, off); s2 += __shfl_xor(s2, off); }
  __shared__ float sa[4], sb[4];
  if ((tid & 63) == 0) { sa[tid >> 6] = s; sb[tid >> 6] = s2; }
  __syncthreads();
  s = sa[0] + sa[1] + sa[2] + sa[3];
  s2 = sb[0] + sb[1] + sb[2] + sb[3];
  const float mean = s * (1.0f / cH);
  const float rstd = rsqrtf(s2 * (1.0f / cH) - mean * mean + 1e-12f);
  float* xr = xo + (size_t)token * cH;
  unsigned short* xbr = xbo + (size_t)token * cH;
#pragma unroll
  for (int i = 0; i < 3; i++) {
    const int c = tid + i * 256;
    const float nv = (v[i] - mean) * rstd * g[c] + be[c];
    xr[c] = nv;
    xbr[c] = f2bf(nv);
  }
}

// ---------------- in-place LayerNorm: x -> x (fp32) + xb (bf16) ----------------
__global__ __launch_bounds__(256) void ln_fused(
    float* __restrict__ x, const float* __restrict__ g,
    const float* __restrict__ be, unsigned short* __restrict__ xbo) {
  const int token = blockIdx.x;
  const int tid = threadIdx.x;
  float* row = x + (size_t)token * cH;
  float v[3];
#pragma unroll
  for (int i = 0; i < 3; i++) v[i] = row[tid + i * 256];
  float s = v[0] + v[1] + v[2];
  float s2 = v[0] * v[0] + v[1] * v[1] + v[2] * v[2];
#pragma unroll
  for (int off = 32; off; off >>= 1) { s += __shfl_xor(s, off); s2 += __shfl_xor(s2, off); }
  __shared__ float sa[4], sb[4];
  if ((tid & 63) == 0) { sa[tid >> 6] = s; sb[tid >> 6] = s2; }
  __syncthreads();
  s = sa[0] + sa[1] + sa[2] + sa[3];
  s2 = sb[0] + sb[1] + sb[2] + sb[3];
  const float mean = s * (1.0f / cH);
  const float rstd = rsqrtf(s2 * (1.0f / cH) - mean * mean + 1e-12f);
  unsigned short* xbr = xbo + (size_t)token * cH;
#pragma unroll
  for (int i = 0; i < 3; i++) {
    const int c = tid + i * 256;
    const float nv = (v[i] - mean) * rstd * g[c] + be[c];
    row[c] = nv;
    xbr[c] = f2bf(nv);
  }
}

// ---------------- flash attention, MFMA 16x16x32 bf16 (fused qkv input) -------
__global__ __launch_bounds__(256, 2) void attn_mfma(
    const unsigned short* __restrict__ qkv, const int* __restrict__ amask,
    unsigned short* __restrict__ ctxb) {
  __shared__ __align__(16) unsigned short Ks[128 * 64];   // [key][physblk*8+j]
  __shared__ __align__(16) unsigned short Vt[64 * 128];   // [d][physblk*8 + key&7]
  __shared__ __align__(16) unsigned short Ps[4 * 32 * 136];
  __shared__ int lensh[4];

  const int tid = threadIdx.x, lane = tid & 63, wave = tid >> 6;
  const int quad = lane >> 4, col = lane & 15;
  const int wg = blockIdx.x;
  const int qb = wg & 3, h = (wg >> 2) % cNH, b = wg / (4 * cNH);
  const int q0 = qb * 128 + wave * 32;  // this wave's first query

  const unsigned short* qg = qkv;
  const unsigned short* kg = qkv + cH;
  const unsigned short* vg = qkv + 2 * cH;

  // sequence length (WG-uniform)
  const int* mrow = amask + b * cS;
  int c = mrow[tid] + mrow[tid + 256];
#pragma unroll
  for (int off = 32; off; off >>= 1) c += __shfl_xor(c, off);
  if (lane == 0) lensh[wave] = c;
  __syncthreads();
  const int len = lensh[0] + lensh[1] + lensh[2] + lensh[3];

  // resident Q fragments (A-operand), 32 queries x 64 d
  const unsigned short* qbase = qg + (size_t)(b * cS + q0) * cQS + h * cDH;
  bh8_t qf[2][2];
#pragma unroll
  for (int mi = 0; mi < 2; mi++)
#pragma unroll
    for (int ks = 0; ks < 2; ks++)
      qf[mi][ks] = *(const bh8_t*)(qbase + (size_t)(mi * 16 + col) * cQS + ks * 32 + quad * 8);

  float mr[2][4], lr[2][4];
  f4_t o[2][4] = {};
#pragma unroll
  for (int mi = 0; mi < 2; mi++)
#pragma unroll
    for (int r = 0; r < 4; r++) { mr[mi][r] = -3.0e38f; lr[mi][r] = 0.0f; }

  unsigned short* Pw = Ps + wave * (32 * 136);

  for (int k0 = 0; k0 < cS; k0 += 128) {
    if (k0 >= len) break;  // remaining tiles fully masked (len WG-uniform)
    __syncthreads();       // prior iter's Ks/Vt reads complete before restage
    const unsigned short* kb = kg + (size_t)(b * cS + k0) * cQS + h * cDH;
    const unsigned short* vb = vg + (size_t)(b * cS + k0) * cQS + h * cDH;
    // K: async16, LDS(key, physblk) <- global d-block (physblk ^ (key&7))
#pragma unroll
    for (int i = 0; i < 4; i++) {
      const int chunk = i * 256 + tid;
      const int key = chunk >> 3;
      const int ld = (chunk & 7) ^ (key & 7);
      async16(Ks + (size_t)(i * 256 + wave * 64) * 8, kb + (size_t)key * cQS + ld * 8);
    }
    // V: manual transpose, Vt[d][pb*8 + key&7], pb = keyblk ^ (d&7) ^ (d>>3)
#pragma unroll
    for (int i = 0; i < 4; i++) {
      const int chunk = i * 256 + tid;
      const int key = chunk >> 3;
      const int ld = chunk & 7;
      const int bk = key >> 3;
      bh8_t vv = *(const bh8_t*)(vb + (size_t)key * cQS + ld * 8);
      unsigned short vs[8];
      *(bh8_t*)vs = vv;
#pragma unroll
      for (int j = 0; j < 8; j++) {
        const int d = ld * 8 + j;
        const int pb = bk ^ j ^ ld;
        Vt[d * 128 + pb * 8 + (key & 7)] = vs[j];
      }
    }
    __syncthreads();  // staging visible (drains vmcnt+lgkmcnt)

    // S = Q K^T (32 q x 128 k per wave)
    f4_t s[2][8];
#pragma unroll
    for (int mi = 0; mi < 2; mi++)
#pragma unroll
      for (int n = 0; n < 8; n++) s[mi][n] = f4_t{0.f, 0.f, 0.f, 0.f};
#pragma unroll
    for (int n = 0; n < 8; n++) {
      const int r = n * 16 + col;  // key row
#pragma unroll
      for (int ks = 0; ks < 2; ks++) {
        const int phys = (ks * 4 + quad) ^ (col & 7);
        bh8_t kf = *(const bh8_t*)(Ks + (size_t)r * 64 + phys * 8);
        s[0][n] = __builtin_amdgcn_mfma_f32_16x16x32_bf16(qf[0][ks], kf, s[0][n], 0, 0, 0);
        s[1][n] = __builtin_amdgcn_mfma_f32_16x16x32_bf16(qf[1][ks], kf, s[1][n], 0, 0, 0);
      }
    }
    // scale + mask
#pragma unroll
    for (int n = 0; n < 8; n++) {
      const bool valid = (k0 + n * 16 + col) < len;
#pragma unroll
      for (int mi = 0; mi < 2; mi++)
#pragma unroll
        for (int r = 0; r < 4; r++)
          s[mi][n][r] = valid ? s[mi][n][r] * 0.125f : -3.0e38f;
    }
    // online softmax per query row (row lives on 16 lanes of one quad)
#pragma unroll
    for (int mi = 0; mi < 2; mi++)
#pragma unroll
      for (int r = 0; r < 4; r++) {
        float v = s[mi][0][r];
#pragma unroll
        for (int n = 1; n < 8; n++) v = fmaxf(v, s[mi][n][r]);
#pragma unroll
        for (int off = 1; off < 16; off <<= 1) v = fmaxf(v, __shfl_xor(v, off));
        const float nm = fmaxf(mr[mi][r], v);
        const float alpha = __expf(mr[mi][r] - nm);
        float rs = 0.0f;
#pragma unroll
        for (int n = 0; n < 8; n++) {
          const float p = __expf(s[mi][n][r] - nm);
          s[mi][n][r] = p;
          rs += p;
        }
#pragma unroll
        for (int off = 1; off < 16; off <<= 1) rs += __shfl_xor(rs, off);
        lr[mi][r] = lr[mi][r] * alpha + rs;
        mr[mi][r] = nm;
#pragma unroll
        for (int nd = 0; nd < 4; nd++) o[mi][nd][r] *= alpha;
      }
    // P -> LDS (C-layout write), then A-frag reads
#pragma unroll
    for (int mi = 0; mi < 2; mi++)
#pragma unroll
      for (int n = 0; n < 8; n++)
#pragma unroll
        for (int r = 0; r < 4; r++)
          Pw[(mi * 16 + quad * 4 + r) * 136 + n * 16 + col] = f2bf(s[mi][n][r]);
    __syncthreads();
    // O += P V
#pragma unroll
    for (int ks = 0; ks < 4; ks++) {
      bh8_t pf[2];
#pragma unroll
      for (int mi = 0; mi < 2; mi++)
        pf[mi] = *(const bh8_t*)(Pw + (size_t)(mi * 16 + col) * 136 + ks * 32 + quad * 8);
#pragma unroll
      for (int nd = 0; nd < 4; nd++) {
        const int d = nd * 16 + col;
        const int pb = (ks * 4 + quad) ^ (d & 7) ^ (d >> 3);
        bh8_t vf = *(const bh8_t*)(Vt + (size_t)d * 128 + pb * 8);
        o[0][nd] = __builtin_amdgcn_mfma_f32_16x16x32_bf16(pf[0], vf, o[0][nd], 0, 0, 0);
        o[1][nd] = __builtin_amdgcn_mfma_f32_16x16x32_bf16(pf[1], vf, o[1][nd], 0, 0, 0);
      }
    }
  }

  // epilogue: normalize and store ctx (bf16)
#pragma unroll
  for (int mi = 0; mi < 2; mi++)
#pragma unroll
    for (int r = 0; r < 4; r++) {
      const float inv = 1.0f / lr[mi][r];  // len >= 256 so lr > 0
      const int q = q0 + mi * 16 + quad * 4 + r;
      unsigned short* orow = ctxb + (size_t)(b * cS + q) * cH + h * cDH;
#pragma unroll
      for (int nd = 0; nd < 4; nd++) orow[nd * 16 + col] = f2bf(o[mi][nd][r] * inv);
    }
}

// ---------------- classifier head: emissions = x @ cls_w + cls_b ----------------
__global__ __launch_bounds__(256) void cls_head(
    const float* __restrict__ x, const float* __restrict__ w,
    const float* __restrict__ cb, float* __restrict__ em) {
  const int token = blockIdx.x * 4 + (threadIdx.x >> 6);
  const int lane = threadIdx.x & 63;
  const float* xr = x + (size_t)token * cH;
  float p[cT] = {};
  for (int k = lane; k < cH; k += 64) {
    const float xv = xr[k];
    const float* wr = w + k * cT;
#pragma unroll
    for (int t = 0; t < cT; t++) p[t] += xv * wr[t];
  }
#pragma unroll
  for (int t = 0; t < cT; t++) {
    float r = p[t];
#pragma unroll
    for (int off = 32; off; off >>= 1) r += __shfl_xor(r, off);
    if (lane == t) em[(size_t)token * cT + t] = r + cb[t];
  }
}

// ---------------- CRF NLL: chunked log-semiring scan, one block per sequence ----
__global__ __launch_bounds__(1024) void crf(
    const float* __restrict__ em, const int* __restrict__ labels,
    const float* __restrict__ cstart, const float* __restrict__ cend,
    const float* __restrict__ ctrans, float* __restrict__ out) {
  const int b = blockIdx.x;
  const int tid = threadIdx.x;
  const int wave = tid >> 6, lane = tid & 63;
  const int* lab = labels + b * cS;
  const float* eb = em + (size_t)b * cS * cT;

  __shared__ float mats[16][49];
  __shared__ float mbuf[8][49];
  __shared__ int slen;
  __shared__ float snum;
  if (tid == 0) { slen = 0; snum = 0.0f; }
  __syncthreads();

  if (tid < cS) {
    const int valid = (tid == 0) || (lab[tid] != -100);
    const unsigned long long bal = __ballot(valid);
    if (lane == 0) atomicAdd(&slen, __popcll(bal));
  }
  __syncthreads();
  const int len = slen;

  {
    float np = 0.0f;
    if (tid >= 1 && tid < len)
      np = ctrans[lab[tid - 1] * cT + lab[tid]] + eb[tid * cT + lab[tid]];
#pragma unroll
    for (int off = 32; off; off >>= 1) np += __shfl_xor(np, off);
    if (lane == 0) atomicAdd(&snum, np);
  }

  const int ii = (lane < 49) ? lane / 7 : 0;
  const int jj = (lane < 49) ? lane % 7 : 0;
  const int i7 = ii * 7;
  float trk[cT];
#pragma unroll
  for (int k = 0; k < cT; k++) trk[k] = ctrans[k * cT + jj];

  float Nij = (ii == jj) ? 0.0f : -1.0e30f;  // log-semiring identity
  const int s_beg = 1 + 32 * wave;
  const int s_end = min(s_beg + 32, len);
  for (int s = s_beg; s < s_end; s++) {
    const float ej = eb[s * cT + jj];
    float v[cT];
#pragma unroll
    for (int k = 0; k < cT; k++) v[k] = __shfl(Nij, i7 + k) + trk[k];
    float mx = v[0];
#pragma unroll
    for (int k = 1; k < cT; k++) mx = fmaxf(mx, v[k]);
    float ss = 0.0f;
#pragma unroll
    for (int k = 0; k < cT; k++) ss += __expf(v[k] - mx);
    Nij = mx + __logf(ss) + ej;
  }
  if (lane < 49) mats[wave][lane] = Nij;
  __syncthreads();

  auto compose = [&](const float* Am, const float* Bm) -> float {
    float v[cT];
#pragma unroll
    for (int k = 0; k < cT; k++) v[k] = Am[i7 + k] + Bm[k * 7 + jj];
    float mx = v[0];
#pragma unroll
    for (int k = 1; k < cT; k++) mx = fmaxf(mx, v[k]);
    float ss = 0.0f;
#pragma unroll
    for (int k = 0; k < cT; k++) ss += __expf(v[k] - mx);
    return mx + __logf(ss);
  };
  if (wave < 8 && lane < 49) mbuf[wave][lane] = compose(mats[2 * wave], mats[2 * wave + 1]);
  __syncthreads();
  if (wave < 4 && lane < 49) mats[wave][lane] = compose(mbuf[2 * wave], mbuf[2 * wave + 1]);
  __syncthreads();
  if (wave < 2 && lane < 49) mbuf[wave][lane] = compose(mats[2 * wave], mats[2 * wave + 1]);
  __syncthreads();

  if (wave == 0) {
    float Mij = compose(mbuf[0], mbuf[1]);
    const float a0 = cstart[ii] + eb[ii];
    const float t = a0 + Mij;
    float av[cT];
#pragma unroll
    for (int k = 0; k < cT; k++) av[k] = __shfl(t, k * 7 + lane);  // valid for lane<7
    float mx = av[0];
#pragma unroll
    for (int k = 1; k < cT; k++) mx = fmaxf(mx, av[k]);
    float ss = 0.0f;
#pragma unroll
    for (int k = 0; k < cT; k++) ss += __expf(av[k] - mx);
    const float afin = mx + __logf(ss) + ((lane < cT) ? cend[lane] : 0.0f);
    float dv[cT];
#pragma unroll
    for (int k = 0; k < cT; k++) dv[k] = __shfl(afin, k);
    float dmx = dv[0];
#pragma unroll
    for (int k = 1; k < cT; k++) dmx = fmaxf(dmx, dv[k]);
    float dss = 0.0f;
#pragma unroll
    for (int k = 0; k < cT; k++) dss += __expf(dv[k] - dmx);
    const float denom = dmx + __logf(dss);
    if (lane == 0) {
      const int l0 = lab[0];
      const float num = snum + cstart[l0] + eb[l0] + cend[lab[len - 1]];
      atomicAdd(out, (denom - num) * (1.0f / cB));
    }
  }
}

// ---------------- launch ----------------
extern "C" void kernel_launch(void* const* d_in, const int* in_sizes, int n_in,
                              void* d_out, int out_size, void* d_ws, size_t ws_size,
                              hipStream_t stream) {
  const float* word_emb = (const float*)d_in[0];
  const float* pos_emb = (const float*)d_in[1];
  const float* emb_ln_s = (const float*)d_in[2];
  const float* emb_ln_b = (const float*)d_in[3];
  const float* attn_qw = (const float*)d_in[4];
  const float* attn_qb = (const float*)d_in[5];
  const float* attn_kw = (const float*)d_in[6];
  const float* attn_kb = (const float*)d_in[7];
  const float* attn_vw = (const float*)d_in[8];
  const float* attn_vb = (const float*)d_in[9];
  const float* attn_ow = (const float*)d_in[10];
  const float* attn_ob = (const float*)d_in[11];
  const float* ln1_s = (const float*)d_in[12];
  const float* ln1_b = (const float*)d_in[13];
  const float* ffn_w1 = (const float*)d_in[14];
  const float* ffn_b1 = (const float*)d_in[15];
  const float* ffn_w2 = (const float*)d_in[16];
  const float* ffn_b2 = (const float*)d_in[17];
  const float* ln2_s = (const float*)d_in[18];
  const float* ln2_b = (const float*)d_in[19];
  const float* cls_w = (const float*)d_in[20];
  const float* cls_b = (const float*)d_in[21];
  const float* crf_start = (const float*)d_in[22];
  const float* crf_end = (const float*)d_in[23];
  const float* crf_trans = (const float*)d_in[24];
  const int* input_ids = (const int*)d_in[25];
  const int* amask = (const int*)d_in[26];
  const int* labels = (const int*)d_in[27];

  // ---- workspace layout (~191 MB total) ----
  char* ws = (char*)d_ws;
  size_t off = 0;
  auto alloc = [&](size_t bytes) -> void* {
    void* p = ws + off;
    off += (bytes + 255) & ~(size_t)255;
    return p;
  };
  constexpr size_t LW = 7077888;  // bf16 elems of one layer's transposed weights
  unsigned short* Wt = (unsigned short*)alloc(LW * 2);                  // 14.2 MB
  float* qkvb = (float*)alloc(cQS * 4);                                 // 9 KB
  float* x = (float*)alloc((size_t)cM * cH * 4);                        // 50.3 MB
  unsigned short* xb = (unsigned short*)alloc((size_t)cM * cH * 2);     // 25.2 MB
  unsigned short* un = (unsigned short*)alloc((size_t)cM * cFF * 2);    // 100.7 MB
  unsigned short* qkv = un;                       // cM x 2304 (attn phase)
  unsigned short* ctx = un + (size_t)cM * cQS;    // cM x 768
  unsigned short* hb = un;                        // cM x 3072 (FFN phase)
  float* emis = (float*)alloc((size_t)cM * cT * 4);                     // 0.5 MB

  hipMemsetAsync(d_out, 0, sizeof(float) * out_size, stream);

  embed_ln<<<cM, 256, 0, stream>>>(input_ids, word_emb, pos_emb, emb_ln_s, emb_ln_b, x, xb);

  for (int i = 0; i < cL; i++) {
    WtransArgs wa;
    wa.src[0] = attn_qw + (size_t)i * cH * cH;
    wa.src[1] = attn_kw + (size_t)i * cH * cH;
    wa.src[2] = attn_vw + (size_t)i * cH * cH;
    wa.src[3] = attn_ow + (size_t)i * cH * cH;
    wa.src[4] = ffn_w1 + (size_t)i * cH * cFF;
    wa.src[5] = ffn_w2 + (size_t)i * cFF * cH;
    wtrans_all<<<dim3(96, 24, 6), dim3(32, 8), 0, stream>>>(wa, Wt);
    concat_bias<<<9, 256, 0, stream>>>(attn_qb + i * cH, attn_kb + i * cH,
                                       attn_vb + i * cH, qkvb);

    gemm_bf16<false, false, true><<<dim3(cQS / 128, cM / 128), 256, 0, stream>>>(
        xb, Wt, qkvb, nullptr, nullptr, qkv, cQS, cH);
    attn_mfma<<<cB * cNH * 4, 256, 0, stream>>>(qkv, amask, ctx);
    gemm_bf16<true, false, false><<<dim3(cH / 128, cM / 128), 256, 0, stream>>>(
        ctx, Wt + 1769472, attn_ob + i * cH, x, x, nullptr, cH, cH);  // x += ctx@Wo+b
    ln_fused<<<cM, 256, 0, stream>>>(x, ln1_s + i * cH, ln1_b + i * cH, xb);
    gemm_bf16<false, true, true><<<dim3(cFF / 128, cM / 128), 256, 0, stream>>>(
        xb, Wt + 2359296, ffn_b1 + i * cFF, nullptr, nullptr, hb, cFF, cH);
    gemm_bf16<true, false, false><<<dim3(cH / 128, cM / 128), 256, 0, stream>>>(
        hb, Wt + 4718592, ffn_b2 + i * cH, x, x, nullptr, cH, cFF);   // x += h@W2+b
    ln_fused<<<cM, 256, 0, stream>>>(x, ln2_s + i * cH, ln2_b + i * cH, xb);
  }

  cls_head<<<cM / 4, 256, 0, stream>>>(x, cls_w, cls_b, emis);
  crf<<<cB, 1024, 0, stream>>>(emis, labels, crf_start, crf_end, crf_trans, (float*)d_out);
}